// Round 6
// baseline (517.167 us; speedup 1.0000x reference)
//
#include <hip/hip_runtime.h>
#include <math.h>

// ---------------- problem constants ----------------
constexpr int Bn  = 2;
constexpr int HWn = 4096;     // H*W
constexpr int Nn  = 4096;
constexpr int KQn = 32;
constexpr int KNn = 16;
constexpr float INV_R1 = 1.0f/262144.0f;   // exact pow2
constexpr float INV_R2 = 1.0f/131072.0f;   // exact pow2

typedef _Float16 f16x8 __attribute__((ext_vector_type(8)));
typedef _Float16 f16x2 __attribute__((ext_vector_type(2)));
typedef float    f32x4 __attribute__((ext_vector_type(4)));

__device__ __forceinline__ float wred64(float v){
  #pragma unroll
  for (int m = 32; m > 0; m >>= 1) v += __shfl_xor(v, m, 64);
  return v;
}
__device__ __forceinline__ float leakyf(float v){ return v > 0.f ? v : 0.1f*v; }

__device__ __forceinline__ void bn_param(const float* st, int c, float inv_n,
                                         const float* g, const float* e,
                                         float& sc, float& sh){
  float mu  = st[c]*inv_n;
  float var = st[128+c]*inv_n - mu*mu;
  float s   = g[c]*rsqrtf(var + 1e-5f);
  sc = s; sh = e[c] - mu*s;
}

// Cooperatively build one 64-row stage-1 input tile into LDS as f16 [64][104]:
// x-layout per row: [wxyz(3), f2_xyz[idx](3), normW*normF2(64), pad(30)].
constexpr int XT_LD = 104;
__device__ __forceinline__ void build_xtile(
    int m0, const float* __restrict__ wxyz, const float* __restrict__ f2_xyz,
    const float* __restrict__ normW, const float* __restrict__ normF2,
    const int* __restrict__ idxq, _Float16* __restrict__ xt, int tid)
{
  int r = tid >> 2, q = tid & 3;
  int row = m0 + r;
  int p = row >> 5, b = p >> 12;
  int idx = idxq[row];
  unsigned int* d32 = (unsigned int*)(xt + r*XT_LD);
  union { unsigned int u; _Float16 h[2]; } pk;
  if (q == 0){
    const float* wx = wxyz + (size_t)p*3;
    const float* fx = f2_xyz + ((size_t)b*Nn + idx)*3;
    pk.h[0]=(_Float16)wx[0]; pk.h[1]=(_Float16)wx[1]; d32[0]=pk.u;
    pk.h[0]=(_Float16)wx[2]; pk.h[1]=(_Float16)fx[0]; d32[1]=pk.u;
    pk.h[0]=(_Float16)fx[1]; pk.h[1]=(_Float16)fx[2]; d32[2]=pk.u;
  }
  const float4* nw = (const float4*)(normW  + (size_t)p*64) + q*4;
  const float4* nf = (const float4*)(normF2 + ((size_t)b*Nn + idx)*64) + q*4;
  #pragma unroll
  for (int i=0;i<4;i++){
    float4 a = nw[i], f = nf[i];
    int base = 3 + q*8 + i*2;            // dword index of x-pos 6+16q+4i
    pk.h[0]=(_Float16)(a.x*f.x); pk.h[1]=(_Float16)(a.y*f.y); d32[base]=pk.u;
    pk.h[0]=(_Float16)(a.z*f.z); pk.h[1]=(_Float16)(a.w*f.w); d32[base+1]=pk.u;
  }
  if (q == 3){
    #pragma unroll
    for (int c=35;c<48;c++) d32[c] = 0u;   // x-pos 70..95 zero (matches w1h pad)
  }
}

// Build the 10-channel stage-2 geometry row
__device__ __forceinline__ void build_x10(int row,
    const float* __restrict__ wxyz, const int* __restrict__ idx2, float* x){
  int p = row >> 4, b = p >> 12;
  int idx = idx2[row];
  const float* nw = wxyz + (size_t)p*3;
  const float* gw = wxyz + ((size_t)b*HWn + idx)*3;
  float n0=nw[0],n1=nw[1],n2=nw[2];
  float g0=gw[0],g1=gw[1],g2=gw[2];
  float d0=g0-n0, d1=g1-n1, d2=g2-n2;
  x[0]=n0;x[1]=n1;x[2]=n2; x[3]=g0;x[4]=g1;x[5]=g2;
  x[6]=d0;x[7]=d1;x[8]=d2; x[9]=sqrtf(d0*d0+d1*d1+d2*d2+1e-20f);
}

// ---------------- fused: exact kNN (2 queries/block) + prep ----------------
// Blocks 0..4095: A-problem query pairs (2blk, 2blk+1), K=32.
// Blocks 4096..8191: B-problem query pairs, K=16 (+valid).
// Blocks 8192..12579: prep (norms, wxyz, weight transposes).
// Pairing amortizes the 48KB/block point loads (the pair always shares batch b:
// consecutive query indices cannot straddle a 4096 boundary). The radix-select
// pipeline (round-1 structure) runs twice serially against the same LDS hist.
__global__ __launch_bounds__(256) void k_knn_prep(
    const float* __restrict__ qA, const float* __restrict__ pA, int* __restrict__ oA,
    const float* __restrict__ qB, const float* __restrict__ pB, int* __restrict__ oB,
    float* __restrict__ ovalid,
    const float* __restrict__ lidar_z,
    const float* __restrict__ warped_points, const float* __restrict__ f2_points,
    const float* __restrict__ m1w0, const float* __restrict__ m1w1,
    const float* __restrict__ piw, const float* __restrict__ pcw,
    const float* __restrict__ m2w0, const float* __restrict__ m2w1,
    const float* __restrict__ m3w0, const float* __restrict__ m3w1,
    float* __restrict__ wxyz, float* __restrict__ normW, float* __restrict__ normF2,
    float* __restrict__ piwT, float* __restrict__ pcwT,
    _Float16* __restrict__ w1h, _Float16* __restrict__ w2h,
    _Float16* __restrict__ w3h, _Float16* __restrict__ w4h,
    _Float16* __restrict__ w5h, _Float16* __restrict__ w6h)
{
  int bid = blockIdx.x;
  int tid = threadIdx.x;
  if (bid >= 8192){
    // ---------------- prep branch ----------------
    int blk = bid - 8192;
    if (blk < 4096){
      int lane = tid & 63;
      int p = blk*4 + (tid >> 6);            // 0..16383
      const float* src; float* dst;
      if (p < Bn*HWn){ src = warped_points + (size_t)p*64; dst = normW + (size_t)p*64; }
      else { int q = p - Bn*HWn; src = f2_points + (size_t)q*64; dst = normF2 + (size_t)q*64; }
      float x = src[lane];
      float m = wred64(x) * (1.f/64.f);
      float d = x - m;
      float ss = wred64(d*d);
      float s = fmaxf(sqrtf(ss*(1.f/63.f)), 1e-12f);
      dst[lane] = d / s;
    } else if (blk < 4192){
      int e = (blk-4096)*256 + tid;          // < 24576
      wxyz[e] = qA[e] * lidar_z[e/3];        // qA == warped_xyz
    } else if (blk < 4196){
      int e = (blk-4192)*256 + tid;          // < 1024
      if (e < 384){ piwT[(e & 63)*6  + (e >> 6)] = piw[e]; }
      else if (e < 1024){ int f = e-384; pcwT[(f & 63)*10 + (f >> 6)] = pcw[f]; }
    } else {
      int e = (blk-4196)*256 + tid;          // < 49152
      if (e < 12288){                        // w1h[j][k] : [128 out][96 in-pad]
        int j = e/96, k = e - j*96;
        w1h[e] = (k < 70) ? (_Float16)m1w0[k*128 + j] : (_Float16)0.f;
      } else if (e < 20480){                 // w2h[d][c] : [64][128]
        int f = e - 12288; int d = f >> 7, c = f & 127;
        w2h[f] = (_Float16)m1w1[c*64 + d];
      } else if (e < 28672){                 // w3h[d][c] : [64][128]
        int f = e - 20480; int d = f >> 7, c = f & 127;
        w3h[f] = (_Float16)m2w0[c*64 + d];
      } else if (e < 32768){                 // w4h[d][c] : [64][64]
        int f = e - 28672; int d = f >> 6, c = f & 63;
        w4h[f] = (_Float16)m2w1[c*64 + d];
      } else if (e < 45056){                 // w5h[d][c] : [64][192]
        int f = e - 32768; int d = f/192, c = f - 192*d;
        w5h[f] = (_Float16)m3w0[c*64 + d];
      } else {                               // w6h[d][c] : [64][64]
        int f = e - 45056; int d = f >> 6, c = f & 63;
        w6h[f] = (_Float16)m3w1[c*64 + d];
      }
    }
    return;
  }
  // ---------------- kNN branch: 2 queries per block ----------------
  __shared__ int hist[4096];
  __shared__ int wsum[4];
  __shared__ unsigned int redm[4], redM[4];
  __shared__ int sh_sel, sh_rem, sh_cls, cnt_lt, cnt_eq;
  bool second = bid >= 4096;
  int pairblk = second ? (bid - 4096) : bid;
  int K = second ? KNn : KQn;
  const float* qpts = second ? qB : qA;
  const float* pts  = second ? pB : pA;
  int* oidx = second ? oB : oA;
  int q0 = pairblk*2;                 // queries q0, q0+1 (same b always)
  int b = q0 >> 12;
  int lane = tid & 63, wv = tid >> 6;
  const float* qp = qpts + (size_t)q0*3;
  float qx0=qp[0], qy0=qp[1], qz0=qp[2];
  float qx1=qp[3], qy1=qp[4], qz1=qp[5];
  const float* pb = pts + (size_t)b*Nn*3;
  unsigned int key0[16], key1[16];
  {
    const float4* pb4 = (const float4*)(pb + (size_t)tid*48);  // 16 pts = 48 floats
    #pragma unroll
    for (int c=0;c<4;c++){
      float4 v0 = pb4[c*3], v1 = pb4[c*3+1], v2 = pb4[c*3+2];
      float f[12] = {v0.x,v0.y,v0.z,v0.w, v1.x,v1.y,v1.z,v1.w, v2.x,v2.y,v2.z,v2.w};
      #pragma unroll
      for (int i=0;i<4;i++){
        int ii = c*4 + i;
        float px=f[i*3+0], py=f[i*3+1], pz=f[i*3+2];
        {
          float dx=__fsub_rn(qx0,px), dy=__fsub_rn(qy0,py), dz=__fsub_rn(qz0,pz);
          key0[ii] = __float_as_uint(__fadd_rn(__fadd_rn(__fmul_rn(dx,dx),__fmul_rn(dy,dy)),__fmul_rn(dz,dz)));
        }
        {
          float dx=__fsub_rn(qx1,px), dy=__fsub_rn(qy1,py), dz=__fsub_rn(qz1,pz);
          key1[ii] = __float_as_uint(__fadd_rn(__fadd_rn(__fmul_rn(dx,dx),__fmul_rn(dy,dy)),__fmul_rn(dz,dz)));
        }
      }
    }
  }
  const unsigned int U100 = __float_as_uint(100.0f); // DIST*DIST
  #pragma unroll
  for (int qs=0; qs<2; qs++){
    // zero hist (no outstanding readers: pass-end barrier guards)
    {
      int4 z = {0,0,0,0};
      #pragma unroll
      for (int j=0;j<4;j++) ((int4*)hist)[tid + j*256] = z;
    }
    // block min/max of this query's keys
    unsigned int mn, mx;
    {
      unsigned int k0 = qs ? key1[0] : key0[0];
      mn = k0; mx = k0;
      #pragma unroll
      for (int i=1;i<16;i++){
        unsigned int kk = qs ? key1[i] : key0[i];
        mn = min(mn, kk); mx = max(mx, kk);
      }
      #pragma unroll
      for (int m=32;m>0;m>>=1){
        mn = min(mn, (unsigned int)__shfl_xor((int)mn, m, 64));
        mx = max(mx, (unsigned int)__shfl_xor((int)mx, m, 64));
      }
    }
    if (lane == 0){ redm[wv] = mn; redM[wv] = mx; }
    if (tid == 0){ cnt_lt = 0; cnt_eq = 0; }
    __syncthreads();                                 // #1: hist zeroed, redm/cnt ready
    mn = min(min(redm[0],redm[1]), min(redm[2],redm[3]));
    mx = max(max(redM[0],redM[1]), max(redM[2],redM[3]));
    unsigned int R = mx - mn;
    int L = (R == 0u) ? 0 : (31 - __clz(R));
    int shift = (L > 11) ? (L - 11) : 0;
    // histogram into swizzled slots
    #pragma unroll
    for (int i=0;i<16;i++){
      unsigned int kk = qs ? key1[i] : key0[i];
      unsigned int d = ((kk-mn) >> shift) & 4095u;
      int slot = (int)(((d & 15u) << 8) | (d >> 4));
      atomicAdd(&hist[slot], 1);
    }
    __syncthreads();                                 // #2
    // conflict-free scan: thread tid owns digits [16*tid,16*tid+16) at slots tid+i*256
    {
      int hv[16]; int tot = 0;
      #pragma unroll
      for (int i=0;i<16;i++){ hv[i] = hist[tid + i*256]; tot += hv[i]; }
      int pref = tot;
      #pragma unroll
      for (int m=1;m<64;m<<=1){ int t = __shfl_up(pref, m, 64); if (lane >= m) pref += t; }
      if (lane == 63) wsum[wv] = pref;
      __syncthreads();                               // #3
      int off = 0;
      #pragma unroll
      for (int i=0;i<3;i++) if (i < wv) off += wsum[i];
      pref += off;                                   // inclusive prefix of thread totals
      if (pref >= K && (pref - tot) < K){
        int running = pref - tot;
        bool done = false;
        #pragma unroll
        for (int i=0;i<16;i++){
          if (!done && running + hv[i] >= K){
            sh_sel = tid*16 + i;
            sh_rem = K - running;
            sh_cls = hv[i];
            done = true;
          }
          if (!done) running += hv[i];
        }
      }
    }
    __syncthreads();                                 // #4: sel ready, scan reads done
    unsigned int sel = (unsigned int)sh_sel;
    int rem = sh_rem, cls = sh_cls;
    int nless = K - rem;
    size_t obase = ((size_t)(q0 + qs))*K;
    // classify: strictly-below -> direct output; boundary bin -> candidates (reuse hist)
    #pragma unroll
    for (int i=0;i<16;i++){
      unsigned int kk = qs ? key1[i] : key0[i];
      unsigned int d = ((kk-mn) >> shift) & 4095u;
      if (d < sel){
        int s = atomicAdd(&cnt_lt, 1);
        oidx[obase+s] = tid*16 + i;
        if (second) ovalid[obase+s] = (kk < U100) ? 1.f : 0.f;
      } else if (d == sel){
        int s = atomicAdd(&cnt_eq, 1);
        if (s < 2048){ hist[s] = (int)kk; hist[2048+s] = tid*16 + i; }
      }
    }
    __syncthreads();                                 // #5: candidates staged
    // wave 0: exact rank-select the rem smallest (key, idx) among cls candidates
    if (wv == 0){
      int cc = cls < 2048 ? cls : 2048;
      for (int c = lane; c < cc; c += 64){
        unsigned int kc = (unsigned int)hist[c];
        int ic = hist[2048+c];
        int rank = 0;
        for (int j = 0; j < cc; j++){
          unsigned int kj = (unsigned int)hist[j];
          if (kj < kc || (kj == kc && hist[2048+j] < ic)) rank++;
        }
        if (rank < rem){
          oidx[obase + nless + rank] = ic;
          if (second) ovalid[obase + nless + rank] = (kc < U100) ? 1.f : 0.f;
        }
      }
    }
    __syncthreads();                                 // #6: end of pass (hist reads done)
  }
}

// ---------------- fused: y1 stats (X1 tiles built in LDS, never to HBM) + Gram ----------------
__global__ __launch_bounds__(256) void k_build_stats(
    const float* __restrict__ wxyz, const float* __restrict__ f2_xyz,
    const float* __restrict__ normW, const float* __restrict__ normF2,
    const int* __restrict__ idxq, const int* __restrict__ idx2,
    const _Float16* __restrict__ w1h,
    float* stats, float* __restrict__ gram)
{
  __shared__ float sacc[66];
  int blk = blockIdx.x, tid = threadIdx.x, lane = tid & 63;
  if (blk < 1024){
    __shared__ _Float16 xt[64*XT_LD];
    __shared__ float ssum[128], sssq[128];
    if (tid < 128){ ssum[tid]=0.f; sssq[tid]=0.f; }
    int wave = tid >> 6;
    int quad = lane >> 4, n16 = lane & 15;
    float r1[8], r2[8];
    #pragma unroll
    for (int i=0;i<8;i++){ r1[i]=0.f; r2[i]=0.f; }
    for (int t=0;t<4;t++){
      build_xtile(blk*256 + t*64, wxyz, f2_xyz, normW, normF2, idxq, xt, tid);
      __syncthreads();
      const _Float16* xr = xt + (size_t)(wave*16 + n16)*XT_LD + quad*8;
      f16x8 a0 = *(const f16x8*)(xr);
      f16x8 a1 = *(const f16x8*)(xr + 32);
      f16x8 a2 = *(const f16x8*)(xr + 64);
      #pragma unroll
      for (int nt = 0; nt < 8; nt++){
        const _Float16* wr = w1h + (size_t)(nt*16 + n16)*96 + quad*8;
        f16x8 b0 = *(const f16x8*)(wr);
        f16x8 b1 = *(const f16x8*)(wr + 32);
        f16x8 b2 = *(const f16x8*)(wr + 64);
        f32x4 acc = {0.f,0.f,0.f,0.f};
        acc = __builtin_amdgcn_mfma_f32_16x16x32_f16(a0, b0, acc, 0,0,0);
        acc = __builtin_amdgcn_mfma_f32_16x16x32_f16(a1, b1, acc, 0,0,0);
        acc = __builtin_amdgcn_mfma_f32_16x16x32_f16(a2, b2, acc, 0,0,0);
        float s1 = acc[0]+acc[1]+acc[2]+acc[3];
        float s2 = acc[0]*acc[0]+acc[1]*acc[1]+acc[2]*acc[2]+acc[3]*acc[3];
        s1 += __shfl_xor(s1, 16, 64); s1 += __shfl_xor(s1, 32, 64);
        s2 += __shfl_xor(s2, 16, 64); s2 += __shfl_xor(s2, 32, 64);
        r1[nt] += s1; r2[nt] += s2;
      }
      __syncthreads();                 // xt reads done before next build
    }
    if (quad == 0){
      #pragma unroll
      for (int nt=0;nt<8;nt++){
        atomicAdd(&ssum[nt*16+n16], r1[nt]); atomicAdd(&sssq[nt*16+n16], r2[nt]);
      }
    }
    __syncthreads();
    if (tid < 128){ atomicAdd(&stats[tid], ssum[tid]); atomicAdd(&stats[128+tid], sssq[tid]); }
  } else if (blk < 1088){
    float a[28];
    #pragma unroll
    for (int q=0;q<28;q++) a[q]=0.f;
    int g = (blk-1024)*256 + tid;
    for (int s=0;s<16;s++){
      int row = g + s*16384;
      int p = row >> 5, b = p >> 12;
      int idx = idxq[row];
      const float* wx = wxyz + (size_t)p*3;
      const float* fx = f2_xyz + ((size_t)b*Nn + idx)*3;
      float xt7[7] = {wx[0],wx[1],wx[2],fx[0],fx[1],fx[2],1.f};
      int q=0;
      #pragma unroll
      for (int i=0;i<7;i++)
        #pragma unroll
        for (int j=i;j<7;j++) a[q++] += xt7[i]*xt7[j];
    }
    if (tid < 28) sacc[tid]=0.f;
    __syncthreads();
    #pragma unroll
    for (int q=0;q<28;q++){
      float v = wred64(a[q]);
      if (lane==0) atomicAdd(&sacc[q], v);
    }
    __syncthreads();
    if (tid < 28) atomicAdd(&gram[tid], sacc[tid]);
  } else {
    float a[66];
    #pragma unroll
    for (int q=0;q<66;q++) a[q]=0.f;
    int g = (blk-1088)*256 + tid;
    for (int s=0;s<16;s++){
      int row = g + s*8192;
      float x[10];
      build_x10(row, wxyz, idx2, x);
      float xt11[11] = {x[0],x[1],x[2],x[3],x[4],x[5],x[6],x[7],x[8],x[9],1.f};
      int q=0;
      #pragma unroll
      for (int i=0;i<11;i++)
        #pragma unroll
        for (int j=i;j<11;j++) a[q++] += xt11[i]*xt11[j];
    }
    if (tid < 66) sacc[tid]=0.f;
    __syncthreads();
    #pragma unroll
    for (int q=0;q<66;q++){
      float v = wred64(a[q]);
      if (lane==0) atomicAdd(&sacc[q], v);
    }
    __syncthreads();
    if (tid < 66) atomicAdd(&gram[32+tid], sacc[tid]);
  }
}

// ---------------- MFMA m1: rebuilds X1 tiles in LDS (no HBM X1 read); block 1024 = gram fin ----------------
__global__ __launch_bounds__(256) void k_mfma_m1(
    const float* __restrict__ wxyz, const float* __restrict__ f2_xyz,
    const float* __restrict__ normW, const float* __restrict__ normF2,
    const int* __restrict__ idxq,
    const _Float16* __restrict__ w1h, const _Float16* __restrict__ w2h,
    const float* __restrict__ m1g0, const float* __restrict__ m1e0,
    float* stats, _Float16* __restrict__ y2h,
    const float* __restrict__ gram,
    const float* __restrict__ piw, const float* __restrict__ pib,
    const float* __restrict__ pcw, const float* __restrict__ pcb)
{
  if (blockIdx.x >= 1024){
    int tid = threadIdx.x;
    if (tid < 64){
      int c = tid;
      float wt[7];
      #pragma unroll
      for (int i=0;i<6;i++) wt[i] = piw[i*64+c];
      wt[6] = pib[c];
      const float* G = gram;
      float sum=0.f, ssq=0.f;
      #pragma unroll
      for (int i=0;i<7;i++){
        int offi = i*7 - (i*(i-1))/2;
        sum += wt[i]*G[offi + (6-i)];
        #pragma unroll
        for (int j=0;j<7;j++){
          int ii = i<j? i : j, jj = i<j? j : i;
          int o = ii*7 - (ii*(ii-1))/2 + (jj-ii);
          ssq += wt[i]*wt[j]*G[o];
        }
      }
      stats[2*256+c] = sum; stats[2*256+128+c] = ssq;
    } else if (tid < 128){
      int c = tid-64;
      float wt[11];
      #pragma unroll
      for (int i=0;i<10;i++) wt[i] = pcw[i*64+c];
      wt[10] = pcb[c];
      const float* G = gram + 32;
      float sum=0.f, ssq=0.f;
      #pragma unroll
      for (int i=0;i<11;i++){
        int offi = i*11 - (i*(i-1))/2;
        sum += wt[i]*G[offi + (10-i)];
        #pragma unroll
        for (int j=0;j<11;j++){
          int ii = i<j? i : j, jj = i<j? j : i;
          int o = ii*11 - (ii*(ii-1))/2 + (jj-ii);
          ssq += wt[i]*wt[j]*G[o];
        }
      }
      stats[5*256+c] = sum; stats[5*256+128+c] = ssq;
    }
    return;
  }
  __shared__ _Float16 xt[64*XT_LD];
  __shared__ _Float16 st[64*136];
  __shared__ float sc1[128], sh1[128], ssum[64], sssq[64];
  int tid = threadIdx.x;
  if (tid < 128){
    float s,h; bn_param(stats, tid, INV_R1, m1g0, m1e0, s, h);
    sc1[tid]=s; sh1[tid]=h;
  }
  if (tid < 64){ ssum[tid]=0.f; sssq[tid]=0.f; }
  int wave = tid >> 6, lane = tid & 63;
  int quad = lane >> 4, n16 = lane & 15;
  float r1[4], r2[4];
  #pragma unroll
  for (int i=0;i<4;i++){ r1[i]=0.f; r2[i]=0.f; }
  for (int t=0;t<4;t++){
    build_xtile(blockIdx.x*256 + t*64, wxyz, f2_xyz, normW, normF2, idxq, xt, tid);
    __syncthreads();                   // A: xt ready (also covers sc1/sh1 init at t=0)
    const _Float16* xr = xt + (size_t)(wave*16 + n16)*XT_LD + quad*8;
    f16x8 a0 = *(const f16x8*)(xr);
    f16x8 a1 = *(const f16x8*)(xr + 32);
    f16x8 a2 = *(const f16x8*)(xr + 64);
    #pragma unroll
    for (int nt = 0; nt < 8; nt++){
      const _Float16* wr = w1h + (size_t)(nt*16 + n16)*96 + quad*8;
      f16x8 b0 = *(const f16x8*)(wr);
      f16x8 b1 = *(const f16x8*)(wr + 32);
      f16x8 b2 = *(const f16x8*)(wr + 64);
      f32x4 acc = {0.f,0.f,0.f,0.f};
      acc = __builtin_amdgcn_mfma_f32_16x16x32_f16(a0, b0, acc, 0,0,0);
      acc = __builtin_amdgcn_mfma_f32_16x16x32_f16(a1, b1, acc, 0,0,0);
      acc = __builtin_amdgcn_mfma_f32_16x16x32_f16(a2, b2, acc, 0,0,0);
      int ch = nt*16 + n16;
      float sc = sc1[ch], sh = sh1[ch];
      #pragma unroll
      for (int r=0;r<4;r++){
        float v = leakyf(acc[r]*sc + sh);
        st[(size_t)(wave*16 + quad*4 + r)*136 + ch] = (_Float16)v;
      }
    }
    __syncthreads();                   // B: st ready, xt reads done
    const _Float16* tr = st + (size_t)(wave*16 + n16)*136 + quad*8;
    f16x8 t0 = *(const f16x8*)(tr);
    f16x8 t1 = *(const f16x8*)(tr + 32);
    f16x8 t2 = *(const f16x8*)(tr + 64);
    f16x8 t3 = *(const f16x8*)(tr + 96);
    #pragma unroll
    for (int nt = 0; nt < 4; nt++){
      const _Float16* wr = w2h + (size_t)(nt*16 + n16)*128 + quad*8;
      f16x8 b0 = *(const f16x8*)(wr);
      f16x8 b1 = *(const f16x8*)(wr + 32);
      f16x8 b2 = *(const f16x8*)(wr + 64);
      f16x8 b3 = *(const f16x8*)(wr + 96);
      f32x4 acc = {0.f,0.f,0.f,0.f};
      acc = __builtin_amdgcn_mfma_f32_16x16x32_f16(t0, b0, acc, 0,0,0);
      acc = __builtin_amdgcn_mfma_f32_16x16x32_f16(t1, b1, acc, 0,0,0);
      acc = __builtin_amdgcn_mfma_f32_16x16x32_f16(t2, b2, acc, 0,0,0);
      acc = __builtin_amdgcn_mfma_f32_16x16x32_f16(t3, b3, acc, 0,0,0);
      int ch = nt*16 + n16;
      #pragma unroll
      for (int r=0;r<4;r++){
        int rowg = blockIdx.x*256 + t*64 + wave*16 + quad*4 + r;
        y2h[(size_t)rowg*64 + ch] = (_Float16)acc[r];
      }
      float s1 = acc[0]+acc[1]+acc[2]+acc[3];
      float s2 = acc[0]*acc[0]+acc[1]*acc[1]+acc[2]*acc[2]+acc[3]*acc[3];
      s1 += __shfl_xor(s1, 16, 64); s1 += __shfl_xor(s1, 32, 64);
      s2 += __shfl_xor(s2, 16, 64); s2 += __shfl_xor(s2, 32, 64);
      r1[nt] += s1; r2[nt] += s2;
    }
    // no extra barrier: next build writes xt only; st(t+1) writes happen after A(t+1)
  }
  __syncthreads();
  if (quad == 0){
    #pragma unroll
    for (int nt=0;nt<4;nt++){
      atomicAdd(&ssum[nt*16+n16], r1[nt]); atomicAdd(&sssq[nt*16+n16], r2[nt]);
    }
  }
  __syncthreads();
  if (tid < 64){ atomicAdd(&stats[1*256+tid], ssum[tid]); atomicAdd(&stats[1*256+128+tid], sssq[tid]); }
}

// ---------------- MFMA m2a: 4 tiles/block; u=[pi_enc|feat] in LDS, y3 = u x W3 ----------------
__global__ __launch_bounds__(256) void k_mfma_m2a(
    const float* __restrict__ wxyz, const float* __restrict__ f2_xyz,
    const int* __restrict__ idxq,
    const float* __restrict__ piwT, const float* __restrict__ pib,
    const float* __restrict__ pig, const float* __restrict__ pie,
    const float* __restrict__ m1g1, const float* __restrict__ m1e1,
    const _Float16* __restrict__ y2h, const _Float16* __restrict__ w3h,
    float* stats, _Float16* __restrict__ y3h)
{
  __shared__ _Float16 su[64*136];
  __shared__ float spw[384];
  __shared__ float scp[64], shp[64], sc2[64], sh2[64], ssum[64], sssq[64];
  int tid = threadIdx.x;
  for (int d = tid; d < 384; d += 256) spw[d] = piwT[d];
  if (tid < 64){
    float s,h;
    bn_param(stats+2*256, tid, INV_R1, pig,  pie,  s, h); scp[tid]=s; shp[tid]=h;
    bn_param(stats+1*256, tid, INV_R1, m1g1, m1e1, s, h); sc2[tid]=s; sh2[tid]=h;
    ssum[tid]=0.f; sssq[tid]=0.f;
  }
  __syncthreads();
  int r = tid & 63, cg = tid >> 6;
  int wave = tid >> 6, lane = tid & 63, quad = lane >> 4, n16 = lane & 15;
  float r1[4], r2[4];
  #pragma unroll
  for (int i=0;i<4;i++){ r1[i]=0.f; r2[i]=0.f; }
  for (int t=0;t<4;t++){
    int rowg = blockIdx.x*256 + t*64 + r;
    {
      int p = rowg >> 5, b = p >> 12;
      int idx = idxq[rowg];
      const float* wx = wxyz + (size_t)p*3;
      const float* fx = f2_xyz + ((size_t)b*Nn + idx)*3;
      float x0=wx[0],x1=wx[1],x2=wx[2],x3=fx[0],x4=fx[1],x5=fx[2];
      #pragma unroll
      for (int jj=0;jj<16;jj++){
        int j = cg*16 + jj;
        const float* pw = spw + j*6;
        float e = pib[j] + x0*pw[0]+x1*pw[1]+x2*pw[2]+x3*pw[3]+x4*pw[4]+x5*pw[5];
        su[r*136 + j] = (_Float16)leakyf(e*scp[j] + shp[j]);
      }
      const f16x8* yr = (const f16x8*)(y2h + (size_t)rowg*64 + cg*16);
      f16x8 q0 = yr[0], q1 = yr[1];
      #pragma unroll
      for (int jj=0;jj<8;jj++){
        int c = cg*16 + jj;
        su[r*136 + 64 + c] = (_Float16)leakyf((float)q0[jj]*sc2[c] + sh2[c]);
      }
      #pragma unroll
      for (int jj=0;jj<8;jj++){
        int c = cg*16 + 8 + jj;
        su[r*136 + 64 + c] = (_Float16)leakyf((float)q1[jj]*sc2[c] + sh2[c]);
      }
    }
    __syncthreads();
    const _Float16* ur = su + (size_t)(wave*16 + n16)*136 + quad*8;
    f16x8 a0 = *(const f16x8*)(ur);
    f16x8 a1 = *(const f16x8*)(ur + 32);
    f16x8 a2 = *(const f16x8*)(ur + 64);
    f16x8 a3 = *(const f16x8*)(ur + 96);
    #pragma unroll
    for (int nt = 0; nt < 4; nt++){
      const _Float16* wr = w3h + (size_t)(nt*16 + n16)*128 + quad*8;
      f16x8 b0 = *(const f16x8*)(wr);
      f16x8 b1 = *(const f16x8*)(wr + 32);
      f16x8 b2 = *(const f16x8*)(wr + 64);
      f16x8 b3 = *(const f16x8*)(wr + 96);
      f32x4 acc = {0.f,0.f,0.f,0.f};
      acc = __builtin_amdgcn_mfma_f32_16x16x32_f16(a0, b0, acc, 0,0,0);
      acc = __builtin_amdgcn_mfma_f32_16x16x32_f16(a1, b1, acc, 0,0,0);
      acc = __builtin_amdgcn_mfma_f32_16x16x32_f16(a2, b2, acc, 0,0,0);
      acc = __builtin_amdgcn_mfma_f32_16x16x32_f16(a3, b3, acc, 0,0,0);
      int ch = nt*16 + n16;
      #pragma unroll
      for (int rr=0;rr<4;rr++){
        int rg = blockIdx.x*256 + t*64 + wave*16 + quad*4 + rr;
        y3h[(size_t)rg*64 + ch] = (_Float16)acc[rr];
      }
      float s1 = acc[0]+acc[1]+acc[2]+acc[3];
      float s2 = acc[0]*acc[0]+acc[1]*acc[1]+acc[2]*acc[2]+acc[3]*acc[3];
      s1 += __shfl_xor(s1, 16, 64); s1 += __shfl_xor(s1, 32, 64);
      s2 += __shfl_xor(s2, 16, 64); s2 += __shfl_xor(s2, 32, 64);
      r1[nt] += s1; r2[nt] += s2;
    }
    __syncthreads();
  }
  if (quad == 0){
    #pragma unroll
    for (int nt=0;nt<4;nt++){
      atomicAdd(&ssum[nt*16+n16], r1[nt]); atomicAdd(&sssq[nt*16+n16], r2[nt]);
    }
  }
  __syncthreads();
  if (tid < 64){ atomicAdd(&stats[3*256+tid], ssum[tid]); atomicAdd(&stats[3*256+128+tid], sssq[tid]); }
}

// ---------------- generic MFMA pointwise 64->64, 4 tiles/block ----------------
__global__ __launch_bounds__(256) void k_mfma_pw64(
    const _Float16* __restrict__ yin, const _Float16* __restrict__ wh,
    const float* __restrict__ g, const float* __restrict__ e,
    const float* statsIn, float* statsOut, float inv_n,
    _Float16* __restrict__ yout)
{
  __shared__ _Float16 stt[64*72];
  __shared__ float sc[64], sh[64], ssum[64], sssq[64];
  int tid = threadIdx.x;
  if (tid < 64){
    float s,h; bn_param(statsIn, tid, inv_n, g, e, s, h);
    sc[tid]=s; sh[tid]=h; ssum[tid]=0.f; sssq[tid]=0.f;
  }
  __syncthreads();
  int r = tid & 63, cg = tid >> 6;
  int wave = tid >> 6, lane = tid & 63, quad = lane >> 4, n16 = lane & 15;
  float r1[4], r2[4];
  #pragma unroll
  for (int i=0;i<4;i++){ r1[i]=0.f; r2[i]=0.f; }
  for (int t=0;t<4;t++){
    int rowg = blockIdx.x*256 + t*64 + r;
    const f16x8* yr = (const f16x8*)(yin + (size_t)rowg*64 + cg*16);
    f16x8 q0 = yr[0], q1 = yr[1];
    #pragma unroll
    for (int jj=0;jj<8;jj++){
      int c = cg*16 + jj;
      stt[r*72 + c] = (_Float16)leakyf((float)q0[jj]*sc[c] + sh[c]);
    }
    #pragma unroll
    for (int jj=0;jj<8;jj++){
      int c = cg*16 + 8 + jj;
      stt[r*72 + c] = (_Float16)leakyf((float)q1[jj]*sc[c] + sh[c]);
    }
    __syncthreads();
    const _Float16* tr = stt + (size_t)(wave*16 + n16)*72 + quad*8;
    f16x8 a0 = *(const f16x8*)(tr);
    f16x8 a1 = *(const f16x8*)(tr + 32);
    #pragma unroll
    for (int nt = 0; nt < 4; nt++){
      const _Float16* wr = wh + (size_t)(nt*16 + n16)*64 + quad*8;
      f16x8 b0 = *(const f16x8*)(wr);
      f16x8 b1 = *(const f16x8*)(wr + 32);
      f32x4 acc = {0.f,0.f,0.f,0.f};
      acc = __builtin_amdgcn_mfma_f32_16x16x32_f16(a0, b0, acc, 0,0,0);
      acc = __builtin_amdgcn_mfma_f32_16x16x32_f16(a1, b1, acc, 0,0,0);
      int ch = nt*16 + n16;
      #pragma unroll
      for (int rr=0;rr<4;rr++){
        int rg = blockIdx.x*256 + t*64 + wave*16 + quad*4 + rr;
        yout[(size_t)rg*64 + ch] = (_Float16)acc[rr];
      }
      float s1 = acc[0]+acc[1]+acc[2]+acc[3];
      float s2 = acc[0]*acc[0]+acc[1]*acc[1]+acc[2]*acc[2]+acc[3]*acc[3];
      s1 += __shfl_xor(s1, 16, 64); s1 += __shfl_xor(s1, 32, 64);
      s2 += __shfl_xor(s2, 16, 64); s2 += __shfl_xor(s2, 32, 64);
      r1[nt] += s1; r2[nt] += s2;
    }
    __syncthreads();
  }
  if (quad == 0){
    #pragma unroll
    for (int nt=0;nt<4;nt++){
      atomicAdd(&ssum[nt*16+n16], r1[nt]); atomicAdd(&sssq[nt*16+n16], r2[nt]);
    }
  }
  __syncthreads();
  if (tid < 64){ atomicAdd(&statsOut[tid], ssum[tid]); atomicAdd(&statsOut[128+tid], sssq[tid]); }
}

// ---------------- MFMA m3a: 4 tiles/block; v=[pc_enc|wp|pif1_g] (192ch), y5 = v x W5 ----------------
__global__ __launch_bounds__(256) void k_mfma_m3a(
    const float* __restrict__ wxyz, const float* __restrict__ warped_points,
    const _Float16* __restrict__ pif1h, const int* __restrict__ idx2,
    const float* __restrict__ pcwT, const float* __restrict__ pcb,
    const float* __restrict__ pcg, const float* __restrict__ pce,
    const _Float16* __restrict__ w5h,
    float* stats, _Float16* __restrict__ y5h)
{
  __shared__ _Float16 sv[64*200];
  __shared__ float spw[640];
  __shared__ float scp[64], shp[64], ssum[64], sssq[64];
  int tid = threadIdx.x;
  for (int d = tid; d < 640; d += 256) spw[d] = pcwT[d];
  if (tid < 64){
    float s,h; bn_param(stats+5*256, tid, INV_R2, pcg, pce, s, h);
    scp[tid]=s; shp[tid]=h; ssum[tid]=0.f; sssq[tid]=0.f;
  }
  __syncthreads();
  int r = tid & 63, cg = tid >> 6;
  int wave = tid >> 6, lane = tid & 63, quad = lane >> 4, n16 = lane & 15;
  float r1[4], r2[4];
  #pragma unroll
  for (int i=0;i<4;i++){ r1[i]=0.f; r2[i]=0.f; }
  for (int t=0;t<4;t++){
    int rowg = blockIdx.x*256 + t*64 + r;
    {
      int p = rowg >> 4, b = p >> 12;
      int idx = idx2[rowg];
      float x[10];
      build_x10(rowg, wxyz, idx2, x);
      #pragma unroll
      for (int jj=0;jj<16;jj++){
        int j = cg*16 + jj;
        const float* pw = spw + j*10;
        float e = pcb[j];
        #pragma unroll
        for (int i=0;i<10;i++) e += x[i]*pw[i];
        sv[r*200 + j] = (_Float16)leakyf(e*scp[j] + shp[j]);
      }
      const float4* wp = (const float4*)(warped_points + (size_t)p*64 + cg*16);
      #pragma unroll
      for (int v4=0; v4<4; v4++){
        float4 q = wp[v4];
        int c = 64 + cg*16 + v4*4;
        sv[r*200 + c + 0] = (_Float16)q.x;
        sv[r*200 + c + 1] = (_Float16)q.y;
        sv[r*200 + c + 2] = (_Float16)q.z;
        sv[r*200 + c + 3] = (_Float16)q.w;
      }
      const f16x8* pg = (const f16x8*)(pif1h + ((size_t)(b*HWn) + idx)*64 + cg*16);
      f16x8 g0 = pg[0], g1 = pg[1];
      #pragma unroll
      for (int jj=0;jj<8;jj++) sv[r*200 + 128 + cg*16 + jj] = g0[jj];
      #pragma unroll
      for (int jj=0;jj<8;jj++) sv[r*200 + 136 + cg*16 + jj] = g1[jj];
    }
    __syncthreads();
    const _Float16* vr = sv + (size_t)(wave*16 + n16)*200 + quad*8;
    f16x8 a0 = *(const f16x8*)(vr);
    f16x8 a1 = *(const f16x8*)(vr + 32);
    f16x8 a2 = *(const f16x8*)(vr + 64);
    f16x8 a3 = *(const f16x8*)(vr + 96);
    f16x8 a4 = *(const f16x8*)(vr + 128);
    f16x8 a5 = *(const f16x8*)(vr + 160);
    #pragma unroll
    for (int nt = 0; nt < 4; nt++){
      const _Float16* wr = w5h + (size_t)(nt*16 + n16)*192 + quad*8;
      f32x4 acc = {0.f,0.f,0.f,0.f};
      acc = __builtin_amdgcn_mfma_f32_16x16x32_f16(a0, *(const f16x8*)(wr),       acc, 0,0,0);
      acc = __builtin_amdgcn_mfma_f32_16x16x32_f16(a1, *(const f16x8*)(wr + 32),  acc, 0,0,0);
      acc = __builtin_amdgcn_mfma_f32_16x16x32_f16(a2, *(const f16x8*)(wr + 64),  acc, 0,0,0);
      acc = __builtin_amdgcn_mfma_f32_16x16x32_f16(a3, *(const f16x8*)(wr + 96),  acc, 0,0,0);
      acc = __builtin_amdgcn_mfma_f32_16x16x32_f16(a4, *(const f16x8*)(wr + 128), acc, 0,0,0);
      acc = __builtin_amdgcn_mfma_f32_16x16x32_f16(a5, *(const f16x8*)(wr + 160), acc, 0,0,0);
      int ch = nt*16 + n16;
      #pragma unroll
      for (int rr=0;rr<4;rr++){
        int rg = blockIdx.x*256 + t*64 + wave*16 + quad*4 + rr;
        y5h[(size_t)rg*64 + ch] = (_Float16)acc[rr];
      }
      float s1 = acc[0]+acc[1]+acc[2]+acc[3];
      float s2 = acc[0]*acc[0]+acc[1]*acc[1]+acc[2]*acc[2]+acc[3]*acc[3];
      s1 += __shfl_xor(s1, 16, 64); s1 += __shfl_xor(s1, 32, 64);
      s2 += __shfl_xor(s2, 16, 64); s2 += __shfl_xor(s2, 32, 64);
      r1[nt] += s1; r2[nt] += s2;
    }
    __syncthreads();
  }
  if (quad == 0){
    #pragma unroll
    for (int nt=0;nt<4;nt++){
      atomicAdd(&ssum[nt*16+n16], r1[nt]); atomicAdd(&sssq[nt*16+n16], r2[nt]);
    }
  }
  __syncthreads();
  if (tid < 64){ atomicAdd(&stats[6*256+tid], ssum[tid]); atomicAdd(&stats[6*256+128+tid], sssq[tid]); }
}

// ---------------- stage-1 softmax over KQ -> pif1 (f16), f16x2 per thread ----------------
__global__ __launch_bounds__(256) void k_softmax1(
    const _Float16* __restrict__ y2h, const _Float16* __restrict__ y4h,
    const float* stats,
    const float* __restrict__ m1g1, const float* __restrict__ m1e1,
    const float* __restrict__ m2g1, const float* __restrict__ m2e1,
    _Float16* __restrict__ pif1h)
{
  int tid = threadIdx.x;
  int p  = blockIdx.x*8 + (tid >> 5);
  int dp = tid & 31;
  int d0 = 2*dp, d1 = 2*dp + 1;
  float sc2a,sh2a,sc4a,sh4a, sc2b,sh2b,sc4b,sh4b;
  bn_param(stats+1*256, d0, INV_R1, m1g1, m1e1, sc2a, sh2a);
  bn_param(stats+4*256, d0, INV_R1, m2g1, m2e1, sc4a, sh4a);
  bn_param(stats+1*256, d1, INV_R1, m1g1, m1e1, sc2b, sh2b);
  bn_param(stats+4*256, d1, INV_R1, m2g1, m2e1, sc4b, sh4b);
  size_t rb = (size_t)p*KQn;
  const _Float16* y4base = y4h + rb*64 + d0;
  const _Float16* y2base = y2h + rb*64 + d0;
  float va[32], vb[32];
  float mxa = -1e30f, mxb = -1e30f;
  #pragma unroll
  for (int k=0;k<32;k++){
    f16x2 h = *(const f16x2*)(y4base + (size_t)k*64);
    float ta = leakyf((float)h[0]*sc4a + sh4a);
    float tb = leakyf((float)h[1]*sc4b + sh4b);
    va[k] = ta; mxa = fmaxf(mxa, ta);
    vb[k] = tb; mxb = fmaxf(mxb, tb);
  }
  float sea = 0.f, seb = 0.f;
  #pragma unroll
  for (int k=0;k<32;k++){
    float ea = __expf(va[k]-mxa); va[k]=ea; sea += ea;
    float eb = __expf(vb[k]-mxb); vb[k]=eb; seb += eb;
  }
  float inva = 1.f/sea, invb = 1.f/seb;
  float acca = 0.f, accb = 0.f;
  #pragma unroll
  for (int k=0;k<32;k++){
    f16x2 h = *(const f16x2*)(y2base + (size_t)k*64);
    acca += va[k]*leakyf((float)h[0]*sc2a + sh2a);
    accb += vb[k]*leakyf((float)h[1]*sc2b + sh2b);
  }
  f16x2 o; o[0] = (_Float16)(acca*inva); o[1] = (_Float16)(accb*invb);
  *(f16x2*)(pif1h + (size_t)p*64 + d0) = o;
}

// ---------------- stage-2 masked softmax over KN -> out, f16x2 per thread ----------------
__global__ __launch_bounds__(256) void k_softmax2(
    const _Float16* __restrict__ y6h, const _Float16* __restrict__ pif1h,
    const int* __restrict__ idx2, const float* __restrict__ validf,
    const float* stats,
    const float* __restrict__ m3g1, const float* __restrict__ m3e1,
    float* __restrict__ out)
{
  int tid = threadIdx.x;
  int p  = blockIdx.x*8 + (tid >> 5);
  int b  = p >> 12;
  int dp = tid & 31;
  int d0 = 2*dp, d1 = 2*dp + 1;
  float sca,sha,scb,shb;
  bn_param(stats+7*256, d0, INV_R2, m3g1, m3e1, sca, sha);
  bn_param(stats+7*256, d1, INV_R2, m3g1, m3e1, scb, shb);
  size_t rb = (size_t)p*KNn;
  const _Float16* y6base = y6h + rb*64 + d0;
  float va[16], vb[16];
  float mxa = -1e30f, mxb = -1e30f;
  #pragma unroll
  for (int k=0;k<16;k++){
    f16x2 h = *(const f16x2*)(y6base + (size_t)k*64);
    bool ok = validf[rb+k] > 0.5f;
    float ta = ok ? leakyf((float)h[0]*sca + sha) : -1e10f;
    float tb = ok ? leakyf((float)h[1]*scb + shb) : -1e10f;
    va[k] = ta; mxa = fmaxf(mxa, ta);
    vb[k] = tb; mxb = fmaxf(mxb, tb);
  }
  float sea = 0.f, seb = 0.f;
  #pragma unroll
  for (int k=0;k<16;k++){
    float ea = __expf(va[k]-mxa); va[k]=ea; sea += ea;
    float eb = __expf(vb[k]-mxb); vb[k]=eb; seb += eb;
  }
  float inva = 1.f/sea, invb = 1.f/seb;
  float acca = 0.f, accb = 0.f;
  #pragma unroll
  for (int k=0;k<16;k++){
    int idx = idx2[rb+k];
    f16x2 h = *(const f16x2*)(pif1h + ((size_t)(b*HWn) + idx)*64 + d0);
    acca += va[k]*(float)h[0];
    accb += vb[k]*(float)h[1];
  }
  float2 o; o.x = acca*inva; o.y = accb*invb;
  *(float2*)(out + (size_t)p*64 + d0) = o;
}

// ---------------- launcher ----------------
extern "C" void kernel_launch(void* const* d_in, const int* in_sizes, int n_in,
                              void* d_out, int out_size, void* d_ws, size_t ws_size,
                              hipStream_t stream)
{
  (void)in_sizes; (void)n_in; (void)out_size; (void)ws_size;
  const float* xyz_proj      = (const float*)d_in[0];
  const float* warped_xyz    = (const float*)d_in[1];
  const float* warped_points = (const float*)d_in[2];
  const float* f2_xyz        = (const float*)d_in[4];
  const float* f2_points     = (const float*)d_in[5];
  const float* lidar_z       = (const float*)d_in[6];
  const float* m1w0=(const float*)d_in[7],  *m1g0=(const float*)d_in[9],  *m1e0=(const float*)d_in[10];
  const float* m1w1=(const float*)d_in[11], *m1g1=(const float*)d_in[13], *m1e1=(const float*)d_in[14];
  const float* piw =(const float*)d_in[15], *pib =(const float*)d_in[16], *pig =(const float*)d_in[17], *pie =(const float*)d_in[18];
  const float* m2w0=(const float*)d_in[19], *m2g0=(const float*)d_in[21], *m2e0=(const float*)d_in[22];
  const float* m2w1=(const float*)d_in[23], *m2g1=(const float*)d_in[25], *m2e1=(const float*)d_in[26];
  const float* pcw =(const float*)d_in[27], *pcb =(const float*)d_in[28], *pcg =(const float*)d_in[29], *pce =(const float*)d_in[30];
  const float* m3w0=(const float*)d_in[31], *m3g0=(const float*)d_in[33], *m3e0=(const float*)d_in[34];
  const float* m3w1=(const float*)d_in[35], *m3g1=(const float*)d_in[37], *m3e1=(const float*)d_in[38];
  float* out = (float*)d_out;

  float* ws     = (float*)d_ws;
  float* wxyz   = ws;                        // 24576
  float* normW  = wxyz   + 24576;            // 524288
  float* normF2 = normW  + 524288;           // 524288
  float* piwT   = normF2 + 524288;           // 384
  float* pcwT   = piwT   + 384;              // 640
  float* stats  = pcwT   + 640;              // 2048
  float* gram   = stats  + 2048;             // 128
  int*   idxq   = (int*)(gram + 128);        // 262144
  int*   idx2   = idxq   + 262144;           // 131072
  float* validf = (float*)(idx2 + 131072);   // 131072
  _Float16* pif1h = (_Float16*)(validf + 131072);   // 1048576 f16 = 524288 floats
  float* X1f    = validf + 131072 + 524288;  // scratch region (X1 no longer materialized)
  float* y2f    = X1f + 12582912;
  _Float16* y2h = (_Float16*)y2f;            // 16777216 f16 = 8388608 floats
  float* y3f    = y2f + 8388608;
  _Float16* y3h = (_Float16*)y3f;            // 8388608 floats
  float* whb    = y3f + 8388608;             // f16 weights: 49152 f16 = 24576 floats
  _Float16* w1h = (_Float16*)whb;            // 12288
  _Float16* w2h = w1h + 12288;               // 8192
  _Float16* w3h = w2h + 8192;                // 8192
  _Float16* w4h = w3h + 8192;                // 4096
  _Float16* w5h = w4h + 4096;                // 12288
  _Float16* w6h = w5h + 12288;               // 4096
  // aliases (regions dead by the time they're overwritten):
  _Float16* y4h = (_Float16*)X1f;
  _Float16* y5h = (_Float16*)(X1f + 8388608);
  _Float16* y6h = y3h;                       // y3 dead after first k_mfma_pw64

  hipMemsetAsync(stats, 0, (2048+128)*sizeof(float), stream);
  k_knn_prep<<<12580,256,0,stream>>>(warped_xyz, f2_xyz, idxq,
                                     xyz_proj, xyz_proj, idx2, validf,
                                     lidar_z, warped_points, f2_points,
                                     m1w0, m1w1, piw, pcw, m2w0, m2w1, m3w0, m3w1,
                                     wxyz, normW, normF2, piwT, pcwT,
                                     w1h, w2h, w3h, w4h, w5h, w6h);
  k_build_stats<<<1120,256,0,stream>>>(wxyz, f2_xyz, normW, normF2, idxq, idx2,
                                       w1h, stats, gram);
  k_mfma_m1<<<1025,256,0,stream>>>(wxyz, f2_xyz, normW, normF2, idxq,
                                   w1h, w2h, m1g0, m1e0, stats, y2h,
                                   gram, piw, pib, pcw, pcb);
  k_mfma_m2a<<<1024,256,0,stream>>>(wxyz, f2_xyz, idxq, piwT, pib, pig, pie,
                                    m1g1, m1e1, y2h, w3h, stats, y3h);
  k_mfma_pw64<<<1024,256,0,stream>>>(y3h, w4h, m2g0, m2e0,
                                     stats+3*256, stats+4*256, INV_R1, y4h);
  k_softmax1<<<1024,256,0,stream>>>(y2h, y4h, stats, m1g1, m1e1, m2g1, m2e1, pif1h);
  k_mfma_m3a<<<512,256,0,stream>>>(wxyz, warped_points, pif1h, idx2,
                                   pcwT, pcb, pcg, pce, w5h, stats, y5h);
  k_mfma_pw64<<<512,256,0,stream>>>(y5h, w6h, m3g0, m3e0,
                                    stats+6*256, stats+7*256, INV_R2, y6h);
  k_softmax2<<<1024,256,0,stream>>>(y6h, pif1h, idx2, validf, stats, m3g1, m3e1, out);
}

// Round 7
// 490.721 us; speedup vs baseline: 1.0539x; 1.0539x over previous
//
#include <hip/hip_runtime.h>
#include <math.h>

// ---------------- problem constants ----------------
constexpr int Bn  = 2;
constexpr int HWn = 4096;     // H*W
constexpr int Nn  = 4096;
constexpr int KQn = 32;
constexpr int KNn = 16;
constexpr float INV_R1 = 1.0f/262144.0f;   // exact pow2
constexpr float INV_R2 = 1.0f/131072.0f;   // exact pow2

typedef _Float16 f16x8 __attribute__((ext_vector_type(8)));
typedef _Float16 f16x2 __attribute__((ext_vector_type(2)));
typedef float    f32x4 __attribute__((ext_vector_type(4)));

__device__ __forceinline__ float wred64(float v){
  #pragma unroll
  for (int m = 32; m > 0; m >>= 1) v += __shfl_xor(v, m, 64);
  return v;
}
__device__ __forceinline__ float leakyf(float v){ return v > 0.f ? v : 0.1f*v; }

__device__ __forceinline__ void bn_param(const float* st, int c, float inv_n,
                                         const float* g, const float* e,
                                         float& sc, float& sh){
  float mu  = st[c]*inv_n;
  float var = st[128+c]*inv_n - mu*mu;
  float s   = g[c]*rsqrtf(var + 1e-5f);
  sc = s; sh = e[c] - mu*s;
}

// Cooperatively build one 64-row stage-1 input tile into LDS as f16 [64][104]:
// x-layout per row: [wxyz(3), f2_xyz[idx](3), normW*normF2(64), pad(30)].
constexpr int XT_LD = 104;
__device__ __forceinline__ void build_xtile(
    int m0, const float* __restrict__ wxyz, const float* __restrict__ f2_xyz,
    const float* __restrict__ normW, const float* __restrict__ normF2,
    const int* __restrict__ idxq, _Float16* __restrict__ xt, int tid)
{
  int r = tid >> 2, q = tid & 3;
  int row = m0 + r;
  int p = row >> 5, b = p >> 12;
  int idx = idxq[row];
  unsigned int* d32 = (unsigned int*)(xt + r*XT_LD);
  union { unsigned int u; _Float16 h[2]; } pk;
  if (q == 0){
    const float* wx = wxyz + (size_t)p*3;
    const float* fx = f2_xyz + ((size_t)b*Nn + idx)*3;
    pk.h[0]=(_Float16)wx[0]; pk.h[1]=(_Float16)wx[1]; d32[0]=pk.u;
    pk.h[0]=(_Float16)wx[2]; pk.h[1]=(_Float16)fx[0]; d32[1]=pk.u;
    pk.h[0]=(_Float16)fx[1]; pk.h[1]=(_Float16)fx[2]; d32[2]=pk.u;
  }
  const float4* nw = (const float4*)(normW  + (size_t)p*64) + q*4;
  const float4* nf = (const float4*)(normF2 + ((size_t)b*Nn + idx)*64) + q*4;
  #pragma unroll
  for (int i=0;i<4;i++){
    float4 a = nw[i], f = nf[i];
    int base = 3 + q*8 + i*2;            // dword index of x-pos 6+16q+4i
    pk.h[0]=(_Float16)(a.x*f.x); pk.h[1]=(_Float16)(a.y*f.y); d32[base]=pk.u;
    pk.h[0]=(_Float16)(a.z*f.z); pk.h[1]=(_Float16)(a.w*f.w); d32[base+1]=pk.u;
  }
  if (q == 3){
    #pragma unroll
    for (int c=35;c<48;c++) d32[c] = 0u;   // x-pos 70..95 zero (matches w1h pad)
  }
}

// Build the 10-channel stage-2 geometry row
__device__ __forceinline__ void build_x10(int row,
    const float* __restrict__ wxyz, const int* __restrict__ idx2, float* x){
  int p = row >> 4, b = p >> 12;
  int idx = idx2[row];
  const float* nw = wxyz + (size_t)p*3;
  const float* gw = wxyz + ((size_t)b*HWn + idx)*3;
  float n0=nw[0],n1=nw[1],n2=nw[2];
  float g0=gw[0],g1=gw[1],g2=gw[2];
  float d0=g0-n0, d1=g1-n1, d2=g2-n2;
  x[0]=n0;x[1]=n1;x[2]=n2; x[3]=g0;x[4]=g1;x[5]=g2;
  x[6]=d0;x[7]=d1;x[8]=d2; x[9]=sqrtf(d0*d0+d1*d1+d2*d2+1e-20f);
}

// ---------------- fused: exact kNN (blocks 0..16383) + prep (blocks 16384..20771) ----------------
// kNN: round-1 structure (1 query/block, VGPR 32 — the occupancy sweet spot), with
// the radix narrowed to 2048 bins (11-bit digit): halves the hist zeroing
// (2 ds_write_b128/thread) and the scan (8 ds_read + 8-step serial select) while
// keeping the exact algorithm (expected bucket occupancy 2, candidate capacity
// 2048 unchanged). slot(d) = ((d&7)<<8)|(d>>3) -> scan reads hist[tid+i*256],
// i<8, conflict-free; thread tid owns digits [8*tid, 8*tid+8).
__global__ __launch_bounds__(256) void k_knn_prep(
    const float* __restrict__ qA, const float* __restrict__ pA, int* __restrict__ oA,
    const float* __restrict__ qB, const float* __restrict__ pB, int* __restrict__ oB,
    float* __restrict__ ovalid,
    const float* __restrict__ lidar_z,
    const float* __restrict__ warped_points, const float* __restrict__ f2_points,
    const float* __restrict__ m1w0, const float* __restrict__ m1w1,
    const float* __restrict__ piw, const float* __restrict__ pcw,
    const float* __restrict__ m2w0, const float* __restrict__ m2w1,
    const float* __restrict__ m3w0, const float* __restrict__ m3w1,
    float* __restrict__ wxyz, float* __restrict__ normW, float* __restrict__ normF2,
    float* __restrict__ piwT, float* __restrict__ pcwT,
    _Float16* __restrict__ w1h, _Float16* __restrict__ w2h,
    _Float16* __restrict__ w3h, _Float16* __restrict__ w4h,
    _Float16* __restrict__ w5h, _Float16* __restrict__ w6h)
{
  int bid = blockIdx.x;
  int tid = threadIdx.x;
  if (bid >= 16384){
    // ---------------- prep branch ----------------
    int blk = bid - 16384;
    if (blk < 4096){
      int lane = tid & 63;
      int p = blk*4 + (tid >> 6);            // 0..16383
      const float* src; float* dst;
      if (p < Bn*HWn){ src = warped_points + (size_t)p*64; dst = normW + (size_t)p*64; }
      else { int q = p - Bn*HWn; src = f2_points + (size_t)q*64; dst = normF2 + (size_t)q*64; }
      float x = src[lane];
      float m = wred64(x) * (1.f/64.f);
      float d = x - m;
      float ss = wred64(d*d);
      float s = fmaxf(sqrtf(ss*(1.f/63.f)), 1e-12f);
      dst[lane] = d / s;
    } else if (blk < 4192){
      int e = (blk-4096)*256 + tid;          // < 24576
      wxyz[e] = qA[e] * lidar_z[e/3];        // qA == warped_xyz
    } else if (blk < 4196){
      int e = (blk-4192)*256 + tid;          // < 1024
      if (e < 384){ piwT[(e & 63)*6  + (e >> 6)] = piw[e]; }
      else if (e < 1024){ int f = e-384; pcwT[(f & 63)*10 + (f >> 6)] = pcw[f]; }
    } else {
      int e = (blk-4196)*256 + tid;          // < 49152
      if (e < 12288){                        // w1h[j][k] : [128 out][96 in-pad]
        int j = e/96, k = e - j*96;
        w1h[e] = (k < 70) ? (_Float16)m1w0[k*128 + j] : (_Float16)0.f;
      } else if (e < 20480){                 // w2h[d][c] : [64][128]
        int f = e - 12288; int d = f >> 7, c = f & 127;
        w2h[f] = (_Float16)m1w1[c*64 + d];
      } else if (e < 28672){                 // w3h[d][c] : [64][128]
        int f = e - 20480; int d = f >> 7, c = f & 127;
        w3h[f] = (_Float16)m2w0[c*64 + d];
      } else if (e < 32768){                 // w4h[d][c] : [64][64]
        int f = e - 28672; int d = f >> 6, c = f & 63;
        w4h[f] = (_Float16)m2w1[c*64 + d];
      } else if (e < 45056){                 // w5h[d][c] : [64][192]
        int f = e - 32768; int d = f/192, c = f - 192*d;
        w5h[f] = (_Float16)m3w0[c*64 + d];
      } else {                               // w6h[d][c] : [64][64]
        int f = e - 45056; int d = f >> 6, c = f & 63;
        w6h[f] = (_Float16)m3w1[c*64 + d];
      }
    }
    return;
  }
  // ---------------- kNN branch ----------------
  __shared__ int hist[4096];                 // bins in [0,2048); [0..4095] reused for candidates
  __shared__ int wsum[4];
  __shared__ unsigned int redm[4], redM[4];
  __shared__ int sh_sel, sh_rem, sh_cls, cnt_lt, cnt_eq;
  bool second = bid >= 8192;
  int blk = second ? (bid - 8192) : bid;
  int K = second ? KNn : KQn;
  const float* qpts = second ? qB : qA;
  const float* pts  = second ? pB : pA;
  int* oidx = second ? oB : oA;
  int b = blk >> 12;
  int qi = blk & 4095;
  int lane = tid & 63, wv = tid >> 6;
  const float* qp = qpts + ((size_t)(b*HWn+qi))*3;
  float qx=qp[0], qy=qp[1], qz=qp[2];
  const float* pb = pts + (size_t)b*Nn*3;
  unsigned int key[16];
  {
    const float4* pb4 = (const float4*)(pb + (size_t)tid*48);  // 16 pts = 48 floats
    float4 v[12];
    #pragma unroll
    for (int i=0;i<12;i++) v[i] = pb4[i];
    const float* f = (const float*)v;
    #pragma unroll
    for (int i=0;i<16;i++){
      float dx = __fsub_rn(qx, f[i*3+0]);
      float dy = __fsub_rn(qy, f[i*3+1]);
      float dz = __fsub_rn(qz, f[i*3+2]);
      float d2 = __fadd_rn(__fadd_rn(__fmul_rn(dx,dx), __fmul_rn(dy,dy)), __fmul_rn(dz,dz));
      key[i] = __float_as_uint(d2);        // nonneg floats: uint order == float order
    }
  }
  // zero hist bins [0,2048) (overlaps the min/max reduce; no prior readers)
  {
    int4 z = {0,0,0,0};
    #pragma unroll
    for (int j=0;j<2;j++) ((int4*)hist)[tid + j*256] = z;
  }
  // block min/max of keys
  unsigned int mn = key[0], mx = key[0];
  #pragma unroll
  for (int i=1;i<16;i++){ mn = min(mn, key[i]); mx = max(mx, key[i]); }
  #pragma unroll
  for (int m=32;m>0;m>>=1){
    mn = min(mn, (unsigned int)__shfl_xor((int)mn, m, 64));
    mx = max(mx, (unsigned int)__shfl_xor((int)mx, m, 64));
  }
  if (lane == 0){ redm[wv] = mn; redM[wv] = mx; }
  if (tid == 0){ cnt_lt = 0; cnt_eq = 0; }
  __syncthreads();                                   // #1
  mn = min(min(redm[0],redm[1]), min(redm[2],redm[3]));
  mx = max(max(redM[0],redM[1]), max(redM[2],redM[3]));
  unsigned int R = mx - mn;
  int L = (R == 0u) ? 0 : (31 - __clz(R));
  int shift = (L > 10) ? (L - 10) : 0;
  // histogram into swizzled slots
  #pragma unroll
  for (int i=0;i<16;i++){
    unsigned int d = ((key[i]-mn) >> shift) & 2047u;
    int slot = (int)(((d & 7u) << 8) | (d >> 3));
    atomicAdd(&hist[slot], 1);
  }
  __syncthreads();                                   // #2
  // conflict-free scan: thread tid owns digits [8*tid, 8*tid+8) at slots tid + i*256
  {
    int hv[8]; int tot = 0;
    #pragma unroll
    for (int i=0;i<8;i++){ hv[i] = hist[tid + i*256]; tot += hv[i]; }
    int pref = tot;
    #pragma unroll
    for (int m=1;m<64;m<<=1){ int t = __shfl_up(pref, m, 64); if (lane >= m) pref += t; }
    if (lane == 63) wsum[wv] = pref;
    __syncthreads();                                 // #3
    int off = 0;
    #pragma unroll
    for (int i=0;i<3;i++) if (i < wv) off += wsum[i];
    pref += off;                                     // inclusive prefix of thread totals
    if (pref >= K && (pref - tot) < K){
      int running = pref - tot;
      bool done = false;
      #pragma unroll
      for (int i=0;i<8;i++){
        if (!done && running + hv[i] >= K){
          sh_sel = tid*8 + i;
          sh_rem = K - running;
          sh_cls = hv[i];
          done = true;
        }
        if (!done) running += hv[i];
      }
    }
  }
  __syncthreads();                                   // #4 (also: all scan reads of hist done)
  unsigned int sel = (unsigned int)sh_sel;
  int rem = sh_rem, cls = sh_cls;
  int nless = K - rem;
  size_t obase = ((size_t)(b*HWn+qi))*K;
  const unsigned int U100 = __float_as_uint(100.0f); // DIST*DIST
  // classify: strictly-below -> direct output; boundary bin -> candidate list (reuse hist)
  #pragma unroll
  for (int i=0;i<16;i++){
    unsigned int d = ((key[i]-mn) >> shift) & 2047u;
    if (d < sel){
      int s = atomicAdd(&cnt_lt, 1);
      oidx[obase+s] = tid*16 + i;
      if (second) ovalid[obase+s] = (key[i] < U100) ? 1.f : 0.f;
    } else if (d == sel){
      int s = atomicAdd(&cnt_eq, 1);
      if (s < 2048){ hist[s] = (int)key[i]; hist[2048+s] = tid*16 + i; }
    }
  }
  __syncthreads();                                   // #5
  // wave 0: exact rank-select the rem smallest (key, idx) among cls candidates.
  if (wv == 0){
    int cc = cls < 2048 ? cls : 2048;
    for (int c = lane; c < cc; c += 64){
      unsigned int kc = (unsigned int)hist[c];
      int ic = hist[2048+c];
      int rank = 0;
      for (int j = 0; j < cc; j++){
        unsigned int kj = (unsigned int)hist[j];
        if (kj < kc || (kj == kc && hist[2048+j] < ic)) rank++;
      }
      if (rank < rem){
        oidx[obase + nless + rank] = ic;
        if (second) ovalid[obase + nless + rank] = (kc < U100) ? 1.f : 0.f;
      }
    }
  }
}

// ---------------- fused: y1 stats (X1 tiles built in LDS, never to HBM) + Gram ----------------
__global__ __launch_bounds__(256) void k_build_stats(
    const float* __restrict__ wxyz, const float* __restrict__ f2_xyz,
    const float* __restrict__ normW, const float* __restrict__ normF2,
    const int* __restrict__ idxq, const int* __restrict__ idx2,
    const _Float16* __restrict__ w1h,
    float* stats, float* __restrict__ gram)
{
  __shared__ float sacc[66];
  int blk = blockIdx.x, tid = threadIdx.x, lane = tid & 63;
  if (blk < 1024){
    __shared__ _Float16 xt[64*XT_LD];
    __shared__ float ssum[128], sssq[128];
    if (tid < 128){ ssum[tid]=0.f; sssq[tid]=0.f; }
    int wave = tid >> 6;
    int quad = lane >> 4, n16 = lane & 15;
    float r1[8], r2[8];
    #pragma unroll
    for (int i=0;i<8;i++){ r1[i]=0.f; r2[i]=0.f; }
    for (int t=0;t<4;t++){
      build_xtile(blk*256 + t*64, wxyz, f2_xyz, normW, normF2, idxq, xt, tid);
      __syncthreads();
      const _Float16* xr = xt + (size_t)(wave*16 + n16)*XT_LD + quad*8;
      f16x8 a0 = *(const f16x8*)(xr);
      f16x8 a1 = *(const f16x8*)(xr + 32);
      f16x8 a2 = *(const f16x8*)(xr + 64);
      #pragma unroll
      for (int nt = 0; nt < 8; nt++){
        const _Float16* wr = w1h + (size_t)(nt*16 + n16)*96 + quad*8;
        f16x8 b0 = *(const f16x8*)(wr);
        f16x8 b1 = *(const f16x8*)(wr + 32);
        f16x8 b2 = *(const f16x8*)(wr + 64);
        f32x4 acc = {0.f,0.f,0.f,0.f};
        acc = __builtin_amdgcn_mfma_f32_16x16x32_f16(a0, b0, acc, 0,0,0);
        acc = __builtin_amdgcn_mfma_f32_16x16x32_f16(a1, b1, acc, 0,0,0);
        acc = __builtin_amdgcn_mfma_f32_16x16x32_f16(a2, b2, acc, 0,0,0);
        float s1 = acc[0]+acc[1]+acc[2]+acc[3];
        float s2 = acc[0]*acc[0]+acc[1]*acc[1]+acc[2]*acc[2]+acc[3]*acc[3];
        s1 += __shfl_xor(s1, 16, 64); s1 += __shfl_xor(s1, 32, 64);
        s2 += __shfl_xor(s2, 16, 64); s2 += __shfl_xor(s2, 32, 64);
        r1[nt] += s1; r2[nt] += s2;
      }
      __syncthreads();                 // xt reads done before next build
    }
    if (quad == 0){
      #pragma unroll
      for (int nt=0;nt<8;nt++){
        atomicAdd(&ssum[nt*16+n16], r1[nt]); atomicAdd(&sssq[nt*16+n16], r2[nt]);
      }
    }
    __syncthreads();
    if (tid < 128){ atomicAdd(&stats[tid], ssum[tid]); atomicAdd(&stats[128+tid], sssq[tid]); }
  } else if (blk < 1088){
    float a[28];
    #pragma unroll
    for (int q=0;q<28;q++) a[q]=0.f;
    int g = (blk-1024)*256 + tid;
    for (int s=0;s<16;s++){
      int row = g + s*16384;
      int p = row >> 5, b = p >> 12;
      int idx = idxq[row];
      const float* wx = wxyz + (size_t)p*3;
      const float* fx = f2_xyz + ((size_t)b*Nn + idx)*3;
      float xt7[7] = {wx[0],wx[1],wx[2],fx[0],fx[1],fx[2],1.f};
      int q=0;
      #pragma unroll
      for (int i=0;i<7;i++)
        #pragma unroll
        for (int j=i;j<7;j++) a[q++] += xt7[i]*xt7[j];
    }
    if (tid < 28) sacc[tid]=0.f;
    __syncthreads();
    #pragma unroll
    for (int q=0;q<28;q++){
      float v = wred64(a[q]);
      if (lane==0) atomicAdd(&sacc[q], v);
    }
    __syncthreads();
    if (tid < 28) atomicAdd(&gram[tid], sacc[tid]);
  } else {
    float a[66];
    #pragma unroll
    for (int q=0;q<66;q++) a[q]=0.f;
    int g = (blk-1088)*256 + tid;
    for (int s=0;s<16;s++){
      int row = g + s*8192;
      float x[10];
      build_x10(row, wxyz, idx2, x);
      float xt11[11] = {x[0],x[1],x[2],x[3],x[4],x[5],x[6],x[7],x[8],x[9],1.f};
      int q=0;
      #pragma unroll
      for (int i=0;i<11;i++)
        #pragma unroll
        for (int j=i;j<11;j++) a[q++] += xt11[i]*xt11[j];
    }
    if (tid < 66) sacc[tid]=0.f;
    __syncthreads();
    #pragma unroll
    for (int q=0;q<66;q++){
      float v = wred64(a[q]);
      if (lane==0) atomicAdd(&sacc[q], v);
    }
    __syncthreads();
    if (tid < 66) atomicAdd(&gram[32+tid], sacc[tid]);
  }
}

// ---------------- MFMA m1: rebuilds X1 tiles in LDS (no HBM X1 read); block 1024 = gram fin ----------------
__global__ __launch_bounds__(256) void k_mfma_m1(
    const float* __restrict__ wxyz, const float* __restrict__ f2_xyz,
    const float* __restrict__ normW, const float* __restrict__ normF2,
    const int* __restrict__ idxq,
    const _Float16* __restrict__ w1h, const _Float16* __restrict__ w2h,
    const float* __restrict__ m1g0, const float* __restrict__ m1e0,
    float* stats, _Float16* __restrict__ y2h,
    const float* __restrict__ gram,
    const float* __restrict__ piw, const float* __restrict__ pib,
    const float* __restrict__ pcw, const float* __restrict__ pcb)
{
  if (blockIdx.x >= 1024){
    int tid = threadIdx.x;
    if (tid < 64){
      int c = tid;
      float wt[7];
      #pragma unroll
      for (int i=0;i<6;i++) wt[i] = piw[i*64+c];
      wt[6] = pib[c];
      const float* G = gram;
      float sum=0.f, ssq=0.f;
      #pragma unroll
      for (int i=0;i<7;i++){
        int offi = i*7 - (i*(i-1))/2;
        sum += wt[i]*G[offi + (6-i)];
        #pragma unroll
        for (int j=0;j<7;j++){
          int ii = i<j? i : j, jj = i<j? j : i;
          int o = ii*7 - (ii*(ii-1))/2 + (jj-ii);
          ssq += wt[i]*wt[j]*G[o];
        }
      }
      stats[2*256+c] = sum; stats[2*256+128+c] = ssq;
    } else if (tid < 128){
      int c = tid-64;
      float wt[11];
      #pragma unroll
      for (int i=0;i<10;i++) wt[i] = pcw[i*64+c];
      wt[10] = pcb[c];
      const float* G = gram + 32;
      float sum=0.f, ssq=0.f;
      #pragma unroll
      for (int i=0;i<11;i++){
        int offi = i*11 - (i*(i-1))/2;
        sum += wt[i]*G[offi + (10-i)];
        #pragma unroll
        for (int j=0;j<11;j++){
          int ii = i<j? i : j, jj = i<j? j : i;
          int o = ii*11 - (ii*(ii-1))/2 + (jj-ii);
          ssq += wt[i]*wt[j]*G[o];
        }
      }
      stats[5*256+c] = sum; stats[5*256+128+c] = ssq;
    }
    return;
  }
  __shared__ _Float16 xt[64*XT_LD];
  __shared__ _Float16 st[64*136];
  __shared__ float sc1[128], sh1[128], ssum[64], sssq[64];
  int tid = threadIdx.x;
  if (tid < 128){
    float s,h; bn_param(stats, tid, INV_R1, m1g0, m1e0, s, h);
    sc1[tid]=s; sh1[tid]=h;
  }
  if (tid < 64){ ssum[tid]=0.f; sssq[tid]=0.f; }
  int wave = tid >> 6, lane = tid & 63;
  int quad = lane >> 4, n16 = lane & 15;
  float r1[4], r2[4];
  #pragma unroll
  for (int i=0;i<4;i++){ r1[i]=0.f; r2[i]=0.f; }
  for (int t=0;t<4;t++){
    build_xtile(blockIdx.x*256 + t*64, wxyz, f2_xyz, normW, normF2, idxq, xt, tid);
    __syncthreads();                   // A: xt ready (also covers sc1/sh1 init at t=0)
    const _Float16* xr = xt + (size_t)(wave*16 + n16)*XT_LD + quad*8;
    f16x8 a0 = *(const f16x8*)(xr);
    f16x8 a1 = *(const f16x8*)(xr + 32);
    f16x8 a2 = *(const f16x8*)(xr + 64);
    #pragma unroll
    for (int nt = 0; nt < 8; nt++){
      const _Float16* wr = w1h + (size_t)(nt*16 + n16)*96 + quad*8;
      f16x8 b0 = *(const f16x8*)(wr);
      f16x8 b1 = *(const f16x8*)(wr + 32);
      f16x8 b2 = *(const f16x8*)(wr + 64);
      f32x4 acc = {0.f,0.f,0.f,0.f};
      acc = __builtin_amdgcn_mfma_f32_16x16x32_f16(a0, b0, acc, 0,0,0);
      acc = __builtin_amdgcn_mfma_f32_16x16x32_f16(a1, b1, acc, 0,0,0);
      acc = __builtin_amdgcn_mfma_f32_16x16x32_f16(a2, b2, acc, 0,0,0);
      int ch = nt*16 + n16;
      float sc = sc1[ch], sh = sh1[ch];
      #pragma unroll
      for (int r=0;r<4;r++){
        float v = leakyf(acc[r]*sc + sh);
        st[(size_t)(wave*16 + quad*4 + r)*136 + ch] = (_Float16)v;
      }
    }
    __syncthreads();                   // B: st ready, xt reads done
    const _Float16* tr = st + (size_t)(wave*16 + n16)*136 + quad*8;
    f16x8 t0 = *(const f16x8*)(tr);
    f16x8 t1 = *(const f16x8*)(tr + 32);
    f16x8 t2 = *(const f16x8*)(tr + 64);
    f16x8 t3 = *(const f16x8*)(tr + 96);
    #pragma unroll
    for (int nt = 0; nt < 4; nt++){
      const _Float16* wr = w2h + (size_t)(nt*16 + n16)*128 + quad*8;
      f16x8 b0 = *(const f16x8*)(wr);
      f16x8 b1 = *(const f16x8*)(wr + 32);
      f16x8 b2 = *(const f16x8*)(wr + 64);
      f16x8 b3 = *(const f16x8*)(wr + 96);
      f32x4 acc = {0.f,0.f,0.f,0.f};
      acc = __builtin_amdgcn_mfma_f32_16x16x32_f16(t0, b0, acc, 0,0,0);
      acc = __builtin_amdgcn_mfma_f32_16x16x32_f16(t1, b1, acc, 0,0,0);
      acc = __builtin_amdgcn_mfma_f32_16x16x32_f16(t2, b2, acc, 0,0,0);
      acc = __builtin_amdgcn_mfma_f32_16x16x32_f16(t3, b3, acc, 0,0,0);
      int ch = nt*16 + n16;
      #pragma unroll
      for (int r=0;r<4;r++){
        int rowg = blockIdx.x*256 + t*64 + wave*16 + quad*4 + r;
        y2h[(size_t)rowg*64 + ch] = (_Float16)acc[r];
      }
      float s1 = acc[0]+acc[1]+acc[2]+acc[3];
      float s2 = acc[0]*acc[0]+acc[1]*acc[1]+acc[2]*acc[2]+acc[3]*acc[3];
      s1 += __shfl_xor(s1, 16, 64); s1 += __shfl_xor(s1, 32, 64);
      s2 += __shfl_xor(s2, 16, 64); s2 += __shfl_xor(s2, 32, 64);
      r1[nt] += s1; r2[nt] += s2;
    }
    // no extra barrier: next build writes xt only; st(t+1) writes happen after A(t+1)
  }
  __syncthreads();
  if (quad == 0){
    #pragma unroll
    for (int nt=0;nt<4;nt++){
      atomicAdd(&ssum[nt*16+n16], r1[nt]); atomicAdd(&sssq[nt*16+n16], r2[nt]);
    }
  }
  __syncthreads();
  if (tid < 64){ atomicAdd(&stats[1*256+tid], ssum[tid]); atomicAdd(&stats[1*256+128+tid], sssq[tid]); }
}

// ---------------- MFMA m2a: 4 tiles/block; u=[pi_enc|feat] in LDS, y3 = u x W3 ----------------
__global__ __launch_bounds__(256) void k_mfma_m2a(
    const float* __restrict__ wxyz, const float* __restrict__ f2_xyz,
    const int* __restrict__ idxq,
    const float* __restrict__ piwT, const float* __restrict__ pib,
    const float* __restrict__ pig, const float* __restrict__ pie,
    const float* __restrict__ m1g1, const float* __restrict__ m1e1,
    const _Float16* __restrict__ y2h, const _Float16* __restrict__ w3h,
    float* stats, _Float16* __restrict__ y3h)
{
  __shared__ _Float16 su[64*136];
  __shared__ float spw[384];
  __shared__ float scp[64], shp[64], sc2[64], sh2[64], ssum[64], sssq[64];
  int tid = threadIdx.x;
  for (int d = tid; d < 384; d += 256) spw[d] = piwT[d];
  if (tid < 64){
    float s,h;
    bn_param(stats+2*256, tid, INV_R1, pig,  pie,  s, h); scp[tid]=s; shp[tid]=h;
    bn_param(stats+1*256, tid, INV_R1, m1g1, m1e1, s, h); sc2[tid]=s; sh2[tid]=h;
    ssum[tid]=0.f; sssq[tid]=0.f;
  }
  __syncthreads();
  int r = tid & 63, cg = tid >> 6;
  int wave = tid >> 6, lane = tid & 63, quad = lane >> 4, n16 = lane & 15;
  float r1[4], r2[4];
  #pragma unroll
  for (int i=0;i<4;i++){ r1[i]=0.f; r2[i]=0.f; }
  for (int t=0;t<4;t++){
    int rowg = blockIdx.x*256 + t*64 + r;
    {
      int p = rowg >> 5, b = p >> 12;
      int idx = idxq[rowg];
      const float* wx = wxyz + (size_t)p*3;
      const float* fx = f2_xyz + ((size_t)b*Nn + idx)*3;
      float x0=wx[0],x1=wx[1],x2=wx[2],x3=fx[0],x4=fx[1],x5=fx[2];
      #pragma unroll
      for (int jj=0;jj<16;jj++){
        int j = cg*16 + jj;
        const float* pw = spw + j*6;
        float e = pib[j] + x0*pw[0]+x1*pw[1]+x2*pw[2]+x3*pw[3]+x4*pw[4]+x5*pw[5];
        su[r*136 + j] = (_Float16)leakyf(e*scp[j] + shp[j]);
      }
      const f16x8* yr = (const f16x8*)(y2h + (size_t)rowg*64 + cg*16);
      f16x8 q0 = yr[0], q1 = yr[1];
      #pragma unroll
      for (int jj=0;jj<8;jj++){
        int c = cg*16 + jj;
        su[r*136 + 64 + c] = (_Float16)leakyf((float)q0[jj]*sc2[c] + sh2[c]);
      }
      #pragma unroll
      for (int jj=0;jj<8;jj++){
        int c = cg*16 + 8 + jj;
        su[r*136 + 64 + c] = (_Float16)leakyf((float)q1[jj]*sc2[c] + sh2[c]);
      }
    }
    __syncthreads();
    const _Float16* ur = su + (size_t)(wave*16 + n16)*136 + quad*8;
    f16x8 a0 = *(const f16x8*)(ur);
    f16x8 a1 = *(const f16x8*)(ur + 32);
    f16x8 a2 = *(const f16x8*)(ur + 64);
    f16x8 a3 = *(const f16x8*)(ur + 96);
    #pragma unroll
    for (int nt = 0; nt < 4; nt++){
      const _Float16* wr = w3h + (size_t)(nt*16 + n16)*128 + quad*8;
      f16x8 b0 = *(const f16x8*)(wr);
      f16x8 b1 = *(const f16x8*)(wr + 32);
      f16x8 b2 = *(const f16x8*)(wr + 64);
      f16x8 b3 = *(const f16x8*)(wr + 96);
      f32x4 acc = {0.f,0.f,0.f,0.f};
      acc = __builtin_amdgcn_mfma_f32_16x16x32_f16(a0, b0, acc, 0,0,0);
      acc = __builtin_amdgcn_mfma_f32_16x16x32_f16(a1, b1, acc, 0,0,0);
      acc = __builtin_amdgcn_mfma_f32_16x16x32_f16(a2, b2, acc, 0,0,0);
      acc = __builtin_amdgcn_mfma_f32_16x16x32_f16(a3, b3, acc, 0,0,0);
      int ch = nt*16 + n16;
      #pragma unroll
      for (int rr=0;rr<4;rr++){
        int rg = blockIdx.x*256 + t*64 + wave*16 + quad*4 + rr;
        y3h[(size_t)rg*64 + ch] = (_Float16)acc[rr];
      }
      float s1 = acc[0]+acc[1]+acc[2]+acc[3];
      float s2 = acc[0]*acc[0]+acc[1]*acc[1]+acc[2]*acc[2]+acc[3]*acc[3];
      s1 += __shfl_xor(s1, 16, 64); s1 += __shfl_xor(s1, 32, 64);
      s2 += __shfl_xor(s2, 16, 64); s2 += __shfl_xor(s2, 32, 64);
      r1[nt] += s1; r2[nt] += s2;
    }
    __syncthreads();
  }
  if (quad == 0){
    #pragma unroll
    for (int nt=0;nt<4;nt++){
      atomicAdd(&ssum[nt*16+n16], r1[nt]); atomicAdd(&sssq[nt*16+n16], r2[nt]);
    }
  }
  __syncthreads();
  if (tid < 64){ atomicAdd(&stats[3*256+tid], ssum[tid]); atomicAdd(&stats[3*256+128+tid], sssq[tid]); }
}

// ---------------- generic MFMA pointwise 64->64, 4 tiles/block ----------------
__global__ __launch_bounds__(256) void k_mfma_pw64(
    const _Float16* __restrict__ yin, const _Float16* __restrict__ wh,
    const float* __restrict__ g, const float* __restrict__ e,
    const float* statsIn, float* statsOut, float inv_n,
    _Float16* __restrict__ yout)
{
  __shared__ _Float16 stt[64*72];
  __shared__ float sc[64], sh[64], ssum[64], sssq[64];
  int tid = threadIdx.x;
  if (tid < 64){
    float s,h; bn_param(statsIn, tid, inv_n, g, e, s, h);
    sc[tid]=s; sh[tid]=h; ssum[tid]=0.f; sssq[tid]=0.f;
  }
  __syncthreads();
  int r = tid & 63, cg = tid >> 6;
  int wave = tid >> 6, lane = tid & 63, quad = lane >> 4, n16 = lane & 15;
  float r1[4], r2[4];
  #pragma unroll
  for (int i=0;i<4;i++){ r1[i]=0.f; r2[i]=0.f; }
  for (int t=0;t<4;t++){
    int rowg = blockIdx.x*256 + t*64 + r;
    const f16x8* yr = (const f16x8*)(yin + (size_t)rowg*64 + cg*16);
    f16x8 q0 = yr[0], q1 = yr[1];
    #pragma unroll
    for (int jj=0;jj<8;jj++){
      int c = cg*16 + jj;
      stt[r*72 + c] = (_Float16)leakyf((float)q0[jj]*sc[c] + sh[c]);
    }
    #pragma unroll
    for (int jj=0;jj<8;jj++){
      int c = cg*16 + 8 + jj;
      stt[r*72 + c] = (_Float16)leakyf((float)q1[jj]*sc[c] + sh[c]);
    }
    __syncthreads();
    const _Float16* tr = stt + (size_t)(wave*16 + n16)*72 + quad*8;
    f16x8 a0 = *(const f16x8*)(tr);
    f16x8 a1 = *(const f16x8*)(tr + 32);
    #pragma unroll
    for (int nt = 0; nt < 4; nt++){
      const _Float16* wr = wh + (size_t)(nt*16 + n16)*64 + quad*8;
      f16x8 b0 = *(const f16x8*)(wr);
      f16x8 b1 = *(const f16x8*)(wr + 32);
      f32x4 acc = {0.f,0.f,0.f,0.f};
      acc = __builtin_amdgcn_mfma_f32_16x16x32_f16(a0, b0, acc, 0,0,0);
      acc = __builtin_amdgcn_mfma_f32_16x16x32_f16(a1, b1, acc, 0,0,0);
      int ch = nt*16 + n16;
      #pragma unroll
      for (int rr=0;rr<4;rr++){
        int rg = blockIdx.x*256 + t*64 + wave*16 + quad*4 + rr;
        yout[(size_t)rg*64 + ch] = (_Float16)acc[rr];
      }
      float s1 = acc[0]+acc[1]+acc[2]+acc[3];
      float s2 = acc[0]*acc[0]+acc[1]*acc[1]+acc[2]*acc[2]+acc[3]*acc[3];
      s1 += __shfl_xor(s1, 16, 64); s1 += __shfl_xor(s1, 32, 64);
      s2 += __shfl_xor(s2, 16, 64); s2 += __shfl_xor(s2, 32, 64);
      r1[nt] += s1; r2[nt] += s2;
    }
    __syncthreads();
  }
  if (quad == 0){
    #pragma unroll
    for (int nt=0;nt<4;nt++){
      atomicAdd(&ssum[nt*16+n16], r1[nt]); atomicAdd(&sssq[nt*16+n16], r2[nt]);
    }
  }
  __syncthreads();
  if (tid < 64){ atomicAdd(&statsOut[tid], ssum[tid]); atomicAdd(&statsOut[128+tid], sssq[tid]); }
}

// ---------------- MFMA m3a: 4 tiles/block; v=[pc_enc|wp|pif1_g] (192ch), y5 = v x W5 ----------------
__global__ __launch_bounds__(256) void k_mfma_m3a(
    const float* __restrict__ wxyz, const float* __restrict__ warped_points,
    const _Float16* __restrict__ pif1h, const int* __restrict__ idx2,
    const float* __restrict__ pcwT, const float* __restrict__ pcb,
    const float* __restrict__ pcg, const float* __restrict__ pce,
    const _Float16* __restrict__ w5h,
    float* stats, _Float16* __restrict__ y5h)
{
  __shared__ _Float16 sv[64*200];
  __shared__ float spw[640];
  __shared__ float scp[64], shp[64], ssum[64], sssq[64];
  int tid = threadIdx.x;
  for (int d = tid; d < 640; d += 256) spw[d] = pcwT[d];
  if (tid < 64){
    float s,h; bn_param(stats+5*256, tid, INV_R2, pcg, pce, s, h);
    scp[tid]=s; shp[tid]=h; ssum[tid]=0.f; sssq[tid]=0.f;
  }
  __syncthreads();
  int r = tid & 63, cg = tid >> 6;
  int wave = tid >> 6, lane = tid & 63, quad = lane >> 4, n16 = lane & 15;
  float r1[4], r2[4];
  #pragma unroll
  for (int i=0;i<4;i++){ r1[i]=0.f; r2[i]=0.f; }
  for (int t=0;t<4;t++){
    int rowg = blockIdx.x*256 + t*64 + r;
    {
      int p = rowg >> 4, b = p >> 12;
      int idx = idx2[rowg];
      float x[10];
      build_x10(rowg, wxyz, idx2, x);
      #pragma unroll
      for (int jj=0;jj<16;jj++){
        int j = cg*16 + jj;
        const float* pw = spw + j*10;
        float e = pcb[j];
        #pragma unroll
        for (int i=0;i<10;i++) e += x[i]*pw[i];
        sv[r*200 + j] = (_Float16)leakyf(e*scp[j] + shp[j]);
      }
      const float4* wp = (const float4*)(warped_points + (size_t)p*64 + cg*16);
      #pragma unroll
      for (int v4=0; v4<4; v4++){
        float4 q = wp[v4];
        int c = 64 + cg*16 + v4*4;
        sv[r*200 + c + 0] = (_Float16)q.x;
        sv[r*200 + c + 1] = (_Float16)q.y;
        sv[r*200 + c + 2] = (_Float16)q.z;
        sv[r*200 + c + 3] = (_Float16)q.w;
      }
      const f16x8* pg = (const f16x8*)(pif1h + ((size_t)(b*HWn) + idx)*64 + cg*16);
      f16x8 g0 = pg[0], g1 = pg[1];
      #pragma unroll
      for (int jj=0;jj<8;jj++) sv[r*200 + 128 + cg*16 + jj] = g0[jj];
      #pragma unroll
      for (int jj=0;jj<8;jj++) sv[r*200 + 136 + cg*16 + jj] = g1[jj];
    }
    __syncthreads();
    const _Float16* vr = sv + (size_t)(wave*16 + n16)*200 + quad*8;
    f16x8 a0 = *(const f16x8*)(vr);
    f16x8 a1 = *(const f16x8*)(vr + 32);
    f16x8 a2 = *(const f16x8*)(vr + 64);
    f16x8 a3 = *(const f16x8*)(vr + 96);
    f16x8 a4 = *(const f16x8*)(vr + 128);
    f16x8 a5 = *(const f16x8*)(vr + 160);
    #pragma unroll
    for (int nt = 0; nt < 4; nt++){
      const _Float16* wr = w5h + (size_t)(nt*16 + n16)*192 + quad*8;
      f32x4 acc = {0.f,0.f,0.f,0.f};
      acc = __builtin_amdgcn_mfma_f32_16x16x32_f16(a0, *(const f16x8*)(wr),       acc, 0,0,0);
      acc = __builtin_amdgcn_mfma_f32_16x16x32_f16(a1, *(const f16x8*)(wr + 32),  acc, 0,0,0);
      acc = __builtin_amdgcn_mfma_f32_16x16x32_f16(a2, *(const f16x8*)(wr + 64),  acc, 0,0,0);
      acc = __builtin_amdgcn_mfma_f32_16x16x32_f16(a3, *(const f16x8*)(wr + 96),  acc, 0,0,0);
      acc = __builtin_amdgcn_mfma_f32_16x16x32_f16(a4, *(const f16x8*)(wr + 128), acc, 0,0,0);
      acc = __builtin_amdgcn_mfma_f32_16x16x32_f16(a5, *(const f16x8*)(wr + 160), acc, 0,0,0);
      int ch = nt*16 + n16;
      #pragma unroll
      for (int rr=0;rr<4;rr++){
        int rg = blockIdx.x*256 + t*64 + wave*16 + quad*4 + rr;
        y5h[(size_t)rg*64 + ch] = (_Float16)acc[rr];
      }
      float s1 = acc[0]+acc[1]+acc[2]+acc[3];
      float s2 = acc[0]*acc[0]+acc[1]*acc[1]+acc[2]*acc[2]+acc[3]*acc[3];
      s1 += __shfl_xor(s1, 16, 64); s1 += __shfl_xor(s1, 32, 64);
      s2 += __shfl_xor(s2, 16, 64); s2 += __shfl_xor(s2, 32, 64);
      r1[nt] += s1; r2[nt] += s2;
    }
    __syncthreads();
  }
  if (quad == 0){
    #pragma unroll
    for (int nt=0;nt<4;nt++){
      atomicAdd(&ssum[nt*16+n16], r1[nt]); atomicAdd(&sssq[nt*16+n16], r2[nt]);
    }
  }
  __syncthreads();
  if (tid < 64){ atomicAdd(&stats[6*256+tid], ssum[tid]); atomicAdd(&stats[6*256+128+tid], sssq[tid]); }
}

// ---------------- stage-1 softmax over KQ -> pif1 (f16), f16x2 per thread ----------------
__global__ __launch_bounds__(256) void k_softmax1(
    const _Float16* __restrict__ y2h, const _Float16* __restrict__ y4h,
    const float* stats,
    const float* __restrict__ m1g1, const float* __restrict__ m1e1,
    const float* __restrict__ m2g1, const float* __restrict__ m2e1,
    _Float16* __restrict__ pif1h)
{
  int tid = threadIdx.x;
  int p  = blockIdx.x*8 + (tid >> 5);
  int dp = tid & 31;
  int d0 = 2*dp, d1 = 2*dp + 1;
  float sc2a,sh2a,sc4a,sh4a, sc2b,sh2b,sc4b,sh4b;
  bn_param(stats+1*256, d0, INV_R1, m1g1, m1e1, sc2a, sh2a);
  bn_param(stats+4*256, d0, INV_R1, m2g1, m2e1, sc4a, sh4a);
  bn_param(stats+1*256, d1, INV_R1, m1g1, m1e1, sc2b, sh2b);
  bn_param(stats+4*256, d1, INV_R1, m2g1, m2e1, sc4b, sh4b);
  size_t rb = (size_t)p*KQn;
  const _Float16* y4base = y4h + rb*64 + d0;
  const _Float16* y2base = y2h + rb*64 + d0;
  float va[32], vb[32];
  float mxa = -1e30f, mxb = -1e30f;
  #pragma unroll
  for (int k=0;k<32;k++){
    f16x2 h = *(const f16x2*)(y4base + (size_t)k*64);
    float ta = leakyf((float)h[0]*sc4a + sh4a);
    float tb = leakyf((float)h[1]*sc4b + sh4b);
    va[k] = ta; mxa = fmaxf(mxa, ta);
    vb[k] = tb; mxb = fmaxf(mxb, tb);
  }
  float sea = 0.f, seb = 0.f;
  #pragma unroll
  for (int k=0;k<32;k++){
    float ea = __expf(va[k]-mxa); va[k]=ea; sea += ea;
    float eb = __expf(vb[k]-mxb); vb[k]=eb; seb += eb;
  }
  float inva = 1.f/sea, invb = 1.f/seb;
  float acca = 0.f, accb = 0.f;
  #pragma unroll
  for (int k=0;k<32;k++){
    f16x2 h = *(const f16x2*)(y2base + (size_t)k*64);
    acca += va[k]*leakyf((float)h[0]*sc2a + sh2a);
    accb += vb[k]*leakyf((float)h[1]*sc2b + sh2b);
  }
  f16x2 o; o[0] = (_Float16)(acca*inva); o[1] = (_Float16)(accb*invb);
  *(f16x2*)(pif1h + (size_t)p*64 + d0) = o;
}

// ---------------- stage-2 masked softmax over KN -> out, f16x2 per thread ----------------
__global__ __launch_bounds__(256) void k_softmax2(
    const _Float16* __restrict__ y6h, const _Float16* __restrict__ pif1h,
    const int* __restrict__ idx2, const float* __restrict__ validf,
    const float* stats,
    const float* __restrict__ m3g1, const float* __restrict__ m3e1,
    float* __restrict__ out)
{
  int tid = threadIdx.x;
  int p  = blockIdx.x*8 + (tid >> 5);
  int b  = p >> 12;
  int dp = tid & 31;
  int d0 = 2*dp, d1 = 2*dp + 1;
  float sca,sha,scb,shb;
  bn_param(stats+7*256, d0, INV_R2, m3g1, m3e1, sca, sha);
  bn_param(stats+7*256, d1, INV_R2, m3g1, m3e1, scb, shb);
  size_t rb = (size_t)p*KNn;
  const _Float16* y6base = y6h + rb*64 + d0;
  float va[16], vb[16];
  float mxa = -1e30f, mxb = -1e30f;
  #pragma unroll
  for (int k=0;k<16;k++){
    f16x2 h = *(const f16x2*)(y6base + (size_t)k*64);
    bool ok = validf[rb+k] > 0.5f;
    float ta = ok ? leakyf((float)h[0]*sca + sha) : -1e10f;
    float tb = ok ? leakyf((float)h[1]*scb + shb) : -1e10f;
    va[k] = ta; mxa = fmaxf(mxa, ta);
    vb[k] = tb; mxb = fmaxf(mxb, tb);
  }
  float sea = 0.f, seb = 0.f;
  #pragma unroll
  for (int k=0;k<16;k++){
    float ea = __expf(va[k]-mxa); va[k]=ea; sea += ea;
    float eb = __expf(vb[k]-mxb); vb[k]=eb; seb += eb;
  }
  float inva = 1.f/sea, invb = 1.f/seb;
  float acca = 0.f, accb = 0.f;
  #pragma unroll
  for (int k=0;k<16;k++){
    int idx = idx2[rb+k];
    f16x2 h = *(const f16x2*)(pif1h + ((size_t)(b*HWn) + idx)*64 + d0);
    acca += va[k]*(float)h[0];
    accb += vb[k]*(float)h[1];
  }
  float2 o; o.x = acca*inva; o.y = accb*invb;
  *(float2*)(out + (size_t)p*64 + d0) = o;
}

// ---------------- launcher ----------------
extern "C" void kernel_launch(void* const* d_in, const int* in_sizes, int n_in,
                              void* d_out, int out_size, void* d_ws, size_t ws_size,
                              hipStream_t stream)
{
  (void)in_sizes; (void)n_in; (void)out_size; (void)ws_size;
  const float* xyz_proj      = (const float*)d_in[0];
  const float* warped_xyz    = (const float*)d_in[1];
  const float* warped_points = (const float*)d_in[2];
  const float* f2_xyz        = (const float*)d_in[4];
  const float* f2_points     = (const float*)d_in[5];
  const float* lidar_z       = (const float*)d_in[6];
  const float* m1w0=(const float*)d_in[7],  *m1g0=(const float*)d_in[9],  *m1e0=(const float*)d_in[10];
  const float* m1w1=(const float*)d_in[11], *m1g1=(const float*)d_in[13], *m1e1=(const float*)d_in[14];
  const float* piw =(const float*)d_in[15], *pib =(const float*)d_in[16], *pig =(const float*)d_in[17], *pie =(const float*)d_in[18];
  const float* m2w0=(const float*)d_in[19], *m2g0=(const float*)d_in[21], *m2e0=(const float*)d_in[22];
  const float* m2w1=(const float*)d_in[23], *m2g1=(const float*)d_in[25], *m2e1=(const float*)d_in[26];
  const float* pcw =(const float*)d_in[27], *pcb =(const float*)d_in[28], *pcg =(const float*)d_in[29], *pce =(const float*)d_in[30];
  const float* m3w0=(const float*)d_in[31], *m3g0=(const float*)d_in[33], *m3e0=(const float*)d_in[34];
  const float* m3w1=(const float*)d_in[35], *m3g1=(const float*)d_in[37], *m3e1=(const float*)d_in[38];
  float* out = (float*)d_out;

  float* ws     = (float*)d_ws;
  float* wxyz   = ws;                        // 24576
  float* normW  = wxyz   + 24576;            // 524288
  float* normF2 = normW  + 524288;           // 524288
  float* piwT   = normF2 + 524288;           // 384
  float* pcwT   = piwT   + 384;              // 640
  float* stats  = pcwT   + 640;              // 2048
  float* gram   = stats  + 2048;             // 128
  int*   idxq   = (int*)(gram + 128);        // 262144
  int*   idx2   = idxq   + 262144;           // 131072
  float* validf = (float*)(idx2 + 131072);   // 131072
  _Float16* pif1h = (_Float16*)(validf + 131072);   // 1048576 f16 = 524288 floats
  float* X1f    = validf + 131072 + 524288;  // scratch region (X1 no longer materialized)
  float* y2f    = X1f + 12582912;
  _Float16* y2h = (_Float16*)y2f;            // 16777216 f16 = 8388608 floats
  float* y3f    = y2f + 8388608;
  _Float16* y3h = (_Float16*)y3f;            // 8388608 floats
  float* whb    = y3f + 8388608;             // f16 weights: 49152 f16 = 24576 floats
  _Float16* w1h = (_Float16*)whb;            // 12288
  _Float16* w2h = w1h + 12288;               // 8192
  _Float16* w3h = w2h + 8192;                // 8192
  _Float16* w4h = w3h + 8192;                // 4096
  _Float16* w5h = w4h + 4096;                // 12288
  _Float16* w6h = w5h + 12288;               // 4096
  // aliases (regions dead by the time they're overwritten):
  _Float16* y4h = (_Float16*)X1f;
  _Float16* y5h = (_Float16*)(X1f + 8388608);
  _Float16* y6h = y3h;                       // y3 dead after first k_mfma_pw64

  hipMemsetAsync(stats, 0, (2048+128)*sizeof(float), stream);
  k_knn_prep<<<20772,256,0,stream>>>(warped_xyz, f2_xyz, idxq,
                                     xyz_proj, xyz_proj, idx2, validf,
                                     lidar_z, warped_points, f2_points,
                                     m1w0, m1w1, piw, pcw, m2w0, m2w1, m3w0, m3w1,
                                     wxyz, normW, normF2, piwT, pcwT,
                                     w1h, w2h, w3h, w4h, w5h, w6h);
  k_build_stats<<<1120,256,0,stream>>>(wxyz, f2_xyz, normW, normF2, idxq, idx2,
                                       w1h, stats, gram);
  k_mfma_m1<<<1025,256,0,stream>>>(wxyz, f2_xyz, normW, normF2, idxq,
                                   w1h, w2h, m1g0, m1e0, stats, y2h,
                                   gram, piw, pib, pcw, pcb);
  k_mfma_m2a<<<1024,256,0,stream>>>(wxyz, f2_xyz, idxq, piwT, pib, pig, pie,
                                    m1g1, m1e1, y2h, w3h, stats, y3h);
  k_mfma_pw64<<<1024,256,0,stream>>>(y3h, w4h, m2g0, m2e0,
                                     stats+3*256, stats+4*256, INV_R1, y4h);
  k_softmax1<<<1024,256,0,stream>>>(y2h, y4h, stats, m1g1, m1e1, m2g1, m2e1, pif1h);
  k_mfma_m3a<<<512,256,0,stream>>>(wxyz, warped_points, pif1h, idx2,
                                   pcwT, pcb, pcg, pce, w5h, stats, y5h);
  k_mfma_pw64<<<512,256,0,stream>>>(y5h, w6h, m3g0, m3e0,
                                    stats+6*256, stats+7*256, INV_R2, y6h);
  k_softmax2<<<1024,256,0,stream>>>(y6h, pif1h, idx2, validf, stats, m3g1, m3e1, out);
}